// Round 8
// baseline (209.052 us; speedup 1.0000x reference)
//
#include <hip/hip_runtime.h>
#include <math.h>

constexpr int B_ = 64;
constexpr int N_ = 1000;
constexpr int D_ = 128;
constexpr int E_ = 20000;
constexpr int BN_TOT = B_ * N_;
constexpr float BN_EPS = 1e-5f;
constexpr float NEG_SLOPE = 0.2f;

typedef __attribute__((ext_vector_type(8))) __bf16 bf16x8;
typedef __attribute__((ext_vector_type(4))) float f32x4;
typedef __attribute__((ext_vector_type(2))) float f32x2;

__device__ __forceinline__ float leaky(float a) { return a >= 0.f ? a : NEG_SLOPE * a; }

__device__ __forceinline__ bf16x8 cvt8(const float* v) {
    bf16x8 h;
#pragma unroll
    for (int j = 0; j < 8; ++j) h[j] = (__bf16)v[j];
    return h;
}

// ---------------- small precompute kernels ----------------

__global__ void k_zero(int* base) {
    int i = threadIdx.x;
    for (int k = i; k < 2304; k += 256) base[k] = 0;
}

__global__ __launch_bounds__(64) void k_emb_scores(const float* __restrict__ emb,
                                                   const float* __restrict__ att_em_i,
                                                   const float* __restrict__ att_em_j,
                                                   float* __restrict__ eemi,
                                                   float* __restrict__ eemj) {
    int n = blockIdx.x;
    int lane = threadIdx.x;
    const float* er = emb + (size_t)n * D_;
    float e0 = er[lane], e1 = er[lane + 64];
    float si = e0 * att_em_i[lane] + e1 * att_em_i[lane + 64];
    float sj = e0 * att_em_j[lane] + e1 * att_em_j[lane + 64];
    for (int off = 32; off > 0; off >>= 1) {
        si += __shfl_down(si, off);
        sj += __shfl_down(sj, off);
    }
    if (lane == 0) { eemi[n] = si; eemj[n] = sj; }
}

__global__ void k_gvec(const float* __restrict__ f_w2, const float* __restrict__ f_b2,
                       const float* __restrict__ out_w, const float* __restrict__ out_b,
                       float* __restrict__ g, float* __restrict__ c0) {
    int j = threadIdx.x;  // 128
    float s = 0.f;
    for (int k = 0; k < D_; ++k) s += out_w[k] * f_w2[k * D_ + j];
    g[j] = s;
    if (j == 0) {
        float c = out_b[0];
        for (int k = 0; k < D_; ++k) c += out_w[k] * f_b2[k];
        *c0 = c;
    }
}

// split weights into bf16 hi/lo: wcat[256][128] = [lin_w ; v_w], f1[128][256] = f_w1
__global__ void k_wprep(const float* __restrict__ lin_w, const float* __restrict__ v_w,
                        const float* __restrict__ f_w1,
                        __bf16* __restrict__ wcat_h, __bf16* __restrict__ wcat_l,
                        __bf16* __restrict__ f1_h, __bf16* __restrict__ f1_l) {
    int i = blockIdx.x * 256 + threadIdx.x;  // 65536 total
    if (i < 32768) {
        float v = (i < 16384) ? lin_w[i] : v_w[i - 16384];
        __bf16 h = (__bf16)v;
        wcat_h[i] = h;
        wcat_l[i] = (__bf16)(v - (float)h);
    } else {
        int j = i - 32768;
        float v = f_w1[j];
        __bf16 h = (__bf16)v;
        f1_h[j] = h;
        f1_l[j] = (__bf16)(v - (float)h);
    }
}

// ---------------- MFMA dual GEMM: [x | t] = data @ [lin_w ; v_w]^T (+v_b on t half) ----------
// A in bf16 (hi only); weights hi+lo (2 MFMA per A-fragment). LDS reads halved vs 3-pass.
__global__ __launch_bounds__(512) void k_mfma_dual(const float* __restrict__ data,
                                                   const __bf16* __restrict__ wcat_h,
                                                   const __bf16* __restrict__ wcat_l,
                                                   const float* __restrict__ v_b,
                                                   float* __restrict__ x,
                                                   float* __restrict__ tmat) {
    const int tid = threadIdx.x;
    const int w = tid >> 6;
    const int l = tid & 63;
    bf16x8 Bh[2][4], Bl[2][4];
#pragma unroll
    for (int nt = 0; nt < 2; ++nt) {
        const int n = w * 32 + nt * 16 + (l & 15);
#pragma unroll
        for (int kk = 0; kk < 4; ++kk) {
            const int k = kk * 32 + (l >> 4) * 8;
            Bh[nt][kk] = *(const bf16x8*)&wcat_h[n * D_ + k];
            Bl[nt][kk] = *(const bf16x8*)&wcat_l[n * D_ + k];
        }
    }
    float vb[2] = {0.f, 0.f};
    if (w >= 4) {
#pragma unroll
        for (int nt = 0; nt < 2; ++nt) vb[nt] = v_b[w * 32 + nt * 16 + (l & 15) - 128];
    }
    __shared__ __align__(16) __bf16 dh[32 * D_];
    const int srow = tid >> 4;
    const int skq = (tid & 15) * 8;
    const int sidx = srow * D_ + (skq ^ ((srow & 7) * 8));
    const int nchunks = BN_TOT / 32;
    for (int ch = blockIdx.x; ch < nchunks; ch += gridDim.x) {
        const int row0 = ch * 32;
        {
            const float* src = data + (size_t)(row0 + srow) * D_ + skq;
            float v[8];
            float4 p0 = *(const float4*)src;
            float4 p1 = *(const float4*)(src + 4);
            v[0] = p0.x; v[1] = p0.y; v[2] = p0.z; v[3] = p0.w;
            v[4] = p1.x; v[5] = p1.y; v[6] = p1.z; v[7] = p1.w;
            *(bf16x8*)&dh[sidx] = cvt8(v);
        }
        __syncthreads();
        f32x4 acc[2][2];
#pragma unroll
        for (int mt = 0; mt < 2; ++mt)
#pragma unroll
            for (int nt = 0; nt < 2; ++nt) acc[mt][nt] = (f32x4){0.f, 0.f, 0.f, 0.f};
#pragma unroll
        for (int mt = 0; mt < 2; ++mt) {
#pragma unroll
            for (int kk = 0; kk < 4; ++kk) {
                const int ai = (mt * 16 + (l & 15)) * D_ + ((kk * 32 + (l >> 4) * 8) ^ ((l & 7) * 8));
                bf16x8 ah = *(const bf16x8*)&dh[ai];
#pragma unroll
                for (int nt = 0; nt < 2; ++nt) {
                    acc[mt][nt] = __builtin_amdgcn_mfma_f32_16x16x32_bf16(ah, Bh[nt][kk], acc[mt][nt], 0, 0, 0);
                    acc[mt][nt] = __builtin_amdgcn_mfma_f32_16x16x32_bf16(ah, Bl[nt][kk], acc[mt][nt], 0, 0, 0);
                }
            }
        }
#pragma unroll
        for (int mt = 0; mt < 2; ++mt) {
#pragma unroll
            for (int nt = 0; nt < 2; ++nt) {
                const int col = w * 32 + nt * 16 + (l & 15);
                const int rg = row0 + mt * 16 + (l >> 4) * 4;
                if (w < 4) {
#pragma unroll
                    for (int r = 0; r < 4; ++r)
                        x[(size_t)(rg + r) * D_ + col] = acc[mt][nt][r];
                } else {
                    const int c2 = col - 128;
#pragma unroll
                    for (int r = 0; r < 4; ++r)
                        tmat[(size_t)(rg + r) * D_ + c2] = acc[mt][nt][r] + vb[nt];
                }
            }
        }
        __syncthreads();
    }
}

// ---------------- node attention scores + packed-bf16 x copy ----------------
__global__ __launch_bounds__(256) void k_scores(const float* __restrict__ x,
                                                const float* __restrict__ att_i,
                                                const float* __restrict__ att_j,
                                                const float* __restrict__ eemi,
                                                const float* __restrict__ eemj,
                                                float* __restrict__ ni, float* __restrict__ nj,
                                                unsigned int* __restrict__ xb) {
    const int wid = threadIdx.x >> 6;
    const int lane = threadIdx.x & 63;
    const int row = blockIdx.x * 4 + wid;
    f32x2 xv = ((const f32x2*)x)[(size_t)row * 64 + lane];
    f32x2 ai = ((const f32x2*)att_i)[lane];
    f32x2 aj = ((const f32x2*)att_j)[lane];
    float si = xv.x * ai.x + xv.y * ai.y;
    float sj = xv.x * aj.x + xv.y * aj.y;
    {
        __bf16 bx = (__bf16)xv.x, by = (__bf16)xv.y;
        unsigned int ux = *(const unsigned short*)&bx;
        unsigned int uy = *(const unsigned short*)&by;
        xb[(size_t)row * 64 + lane] = ux | (uy << 16);
    }
    for (int off = 32; off > 0; off >>= 1) {
        si += __shfl_down(si, off);
        sj += __shfl_down(sj, off);
    }
    if (lane == 0) {
        int n = row % N_;
        ni[row] = si + eemi[n];
        nj[row] = sj + eemj[n];
    }
}

// ---------------- CSR build ----------------
__global__ void k_count(const int* __restrict__ ei, int* __restrict__ offs) {
    int e = blockIdx.x * blockDim.x + threadIdx.x;
    if (e < E_) atomicAdd(&offs[ei[E_ + e] + 1], 1);
}

__global__ __launch_bounds__(1024) void k_scan(int* __restrict__ offs) {
    __shared__ int s[N_ + 1];
    int tid = threadIdx.x;
    if (tid <= N_) s[tid] = offs[tid];
    __syncthreads();
    for (int off = 1; off <= N_; off <<= 1) {
        int v = 0;
        if (tid <= N_) { v = s[tid]; if (tid >= off) v += s[tid - off]; }
        __syncthreads();
        if (tid <= N_) s[tid] = v;
        __syncthreads();
    }
    if (tid <= N_) offs[tid] = s[tid];
}

__global__ void k_scatter(const int* __restrict__ ei, const int* __restrict__ offs,
                          int* __restrict__ cursor, int* __restrict__ csr_src) {
    int e = blockIdx.x * blockDim.x + threadIdx.x;
    if (e < E_) {
        int dn = ei[E_ + e];
        int pos = offs[dn] + atomicAdd(&cursor[dn], 1);
        csr_src[pos] = ei[e];
    }
}

// ---------------- edge softmax: one WAVE per (b,i) ----------------
__global__ __launch_bounds__(256) void k_edge_w(const float* __restrict__ ni,
                                                const float* __restrict__ nj,
                                                const int* __restrict__ offs,
                                                const int* __restrict__ csr_src,
                                                float* __restrict__ exbuf,
                                                float* __restrict__ selfex,
                                                float* __restrict__ denomv) {
    const int wid = threadIdx.x >> 6;
    const int lane = threadIdx.x & 63;
    const int bid = blockIdx.x * 4 + wid;
    const int b = bid / N_;
    const int i = bid - b * N_;
    const int base = b * N_;
    const int e0 = offs[i], e1 = offs[i + 1];
    const float nii = ni[bid];
    const float aself = leaky(nii + nj[bid]);
    float amax = aself;
    for (int e = e0 + lane; e < e1; e += 64) {
        int s = csr_src[e];
        amax = fmaxf(amax, leaky(nii + nj[base + s]));
    }
    for (int off = 32; off > 0; off >>= 1) amax = fmaxf(amax, __shfl_xor(amax, off));
    float sum = 0.f;
    if (lane == 0) {
        float se = __expf(aself - amax);
        selfex[bid] = se;
        sum = se;
    }
    for (int e = e0 + lane; e < e1; e += 64) {
        int s = csr_src[e];
        float ex = __expf(leaky(nii + nj[base + s]) - amax);
        exbuf[(size_t)b * E_ + e] = ex;
        sum += ex;
    }
    for (int off = 32; off > 0; off >>= 1) sum += __shfl_xor(sum, off);
    if (lane == 0) denomv[bid] = sum;
}

// ---------------- SpMM gather-aggregate: wave/segment, bf16 payload, NT agg store ----------
__global__ __launch_bounds__(256) void k_spmm(const unsigned int* __restrict__ xb,
                                              const int* __restrict__ offs,
                                              const int* __restrict__ csr_src,
                                              const float* __restrict__ exbuf,
                                              const float* __restrict__ selfex,
                                              const float* __restrict__ denomv,
                                              const float* __restrict__ gnn_bias,
                                              float* __restrict__ agg) {
    constexpr int CAP = 128;
    __shared__ int s_lds[4][CAP];
    __shared__ float w_lds[4][CAP];
    const int swz = (blockIdx.x & 7) * 2000 + (blockIdx.x >> 3);
    const int w = threadIdx.x >> 6;
    const int l = threadIdx.x & 63;
    const int bid = swz * 4 + w;
    const int b = bid / N_;
    const int i = bid - b * N_;
    const int base = b * N_;
    const int e0 = offs[i];
    const int deg = offs[i + 1] - e0;
    const int stg = deg < CAP ? deg : CAP;
    for (int k = l; k < stg; k += 64) {
        s_lds[w][k] = csr_src[e0 + k];
        w_lds[w][k] = exbuf[(size_t)b * E_ + e0 + k];
    }
    __syncthreads();
    float accx, accy;
    {
        float se = selfex[bid];
        unsigned int u = xb[(size_t)bid * 64 + l];
        accx = se * __uint_as_float(u << 16);
        accy = se * __uint_as_float(u & 0xffff0000u);
    }
    int k = 0;
    for (; k + 8 <= stg; k += 8) {
        unsigned int u[8];
        float wg[8];
#pragma unroll
        for (int j = 0; j < 8; ++j) {
            int s = s_lds[w][k + j];
            wg[j] = w_lds[w][k + j];
            u[j] = xb[(size_t)(base + s) * 64 + l];
        }
#pragma unroll
        for (int j = 0; j < 8; ++j) {
            accx += wg[j] * __uint_as_float(u[j] << 16);
            accy += wg[j] * __uint_as_float(u[j] & 0xffff0000u);
        }
    }
    for (; k < stg; ++k) {
        int s = s_lds[w][k];
        float wg = w_lds[w][k];
        unsigned int u = xb[(size_t)(base + s) * 64 + l];
        accx += wg * __uint_as_float(u << 16);
        accy += wg * __uint_as_float(u & 0xffff0000u);
    }
    for (int e = e0 + CAP; e < e0 + deg; ++e) {
        int s = csr_src[e];
        float wg = exbuf[(size_t)b * E_ + e];
        unsigned int u = xb[(size_t)(base + s) * 64 + l];
        accx += wg * __uint_as_float(u << 16);
        accy += wg * __uint_as_float(u & 0xffff0000u);
    }
    const float dn = 1.f / denomv[bid];
    f32x2 gb = ((const f32x2*)gnn_bias)[l];
    f32x2 o;
    o.x = accx * dn + gb.x;
    o.y = accy * dn + gb.y;
    __builtin_nontemporal_store(o, (f32x2*)agg + (size_t)bid * 64 + l);
}

// ---------------- BatchNorm statistics: two-stage ----------------
__global__ __launch_bounds__(256) void k_bn_part(const float* __restrict__ agg,
                                                 float* __restrict__ partials) {
    const int g = threadIdx.x >> 5;
    const int c4 = threadIdx.x & 31;
    f32x4 s = (f32x4){0.f, 0.f, 0.f, 0.f};
    f32x4 q = (f32x4){0.f, 0.f, 0.f, 0.f};
    for (int r = blockIdx.x * 8 + g; r < BN_TOT; r += 8192) {
        float4 v = *(const float4*)&agg[(size_t)r * D_ + c4 * 4];
        s.x += v.x; s.y += v.y; s.z += v.z; s.w += v.w;
        q.x += v.x * v.x; q.y += v.y * v.y; q.z += v.z * v.z; q.w += v.w * v.w;
    }
    __shared__ f32x4 ls[8][32];
    __shared__ f32x4 lq[8][32];
    ls[g][c4] = s;
    lq[g][c4] = q;
    __syncthreads();
    if (threadIdx.x < 32) {
        f32x4 ts = ls[0][threadIdx.x];
        f32x4 tq = lq[0][threadIdx.x];
#pragma unroll
        for (int gg = 1; gg < 8; ++gg) {
            f32x4 a = ls[gg][threadIdx.x];
            f32x4 b = lq[gg][threadIdx.x];
            ts.x += a.x; ts.y += a.y; ts.z += a.z; ts.w += a.w;
            tq.x += b.x; tq.y += b.y; tq.z += b.z; tq.w += b.w;
        }
        f32x4* p = (f32x4*)partials + (size_t)blockIdx.x * 64;
        p[threadIdx.x] = ts;
        p[32 + threadIdx.x] = tq;
    }
}

__global__ __launch_bounds__(1024) void k_bn_fin2(const float* __restrict__ partials,
                                                  const float* __restrict__ gamma,
                                                  const float* __restrict__ beta,
                                                  float* __restrict__ scale,
                                                  float* __restrict__ shift) {
    const int d = threadIdx.x & 127;
    const int part = threadIdx.x >> 7;
    float s = 0.f, q = 0.f;
    for (int blk = part * 128; blk < part * 128 + 128; ++blk) {
        s += partials[(size_t)blk * 256 + d];
        q += partials[(size_t)blk * 256 + 128 + d];
    }
    __shared__ float lss[8][128];
    __shared__ float lqq[8][128];
    lss[part][d] = s;
    lqq[part][d] = q;
    __syncthreads();
    if (threadIdx.x < 128) {
        float ts = 0.f, tq = 0.f;
#pragma unroll
        for (int p = 0; p < 8; ++p) { ts += lss[p][d]; tq += lqq[p][d]; }
        float mu = ts * (1.f / BN_TOT);
        float var = tq * (1.f / BN_TOT) - mu * mu;
        float sc = gamma[d] * rsqrtf(var + BN_EPS);
        scale[d] = sc;
        shift[d] = beta[d] - mu * sc;
    }
}

// ---------------- MFMA fusion: A in bf16 (hi only), weights hi+lo ----------------
__global__ __launch_bounds__(512) void k_mfma_fusion(const float* __restrict__ agg,
                                                     const float* __restrict__ tmat,
                                                     const __bf16* __restrict__ f1_h,
                                                     const __bf16* __restrict__ f1_l,
                                                     const float* __restrict__ f_b1,
                                                     const float* __restrict__ scale,
                                                     const float* __restrict__ shift,
                                                     const float* __restrict__ g,
                                                     const float* __restrict__ c0p,
                                                     float* __restrict__ out) {
    const int tid = threadIdx.x;
    const int w = tid >> 6;
    const int l = tid & 63;
    const float c0v = *c0p;
    bf16x8 Fh[8], Fl[8];
    const int ncol = w * 16 + (l & 15);
#pragma unroll
    for (int kk = 0; kk < 8; ++kk) {
        const int k = kk * 32 + (l >> 4) * 8;
        Fh[kk] = *(const bf16x8*)&f1_h[ncol * 256 + k];
        Fl[kk] = *(const bf16x8*)&f1_l[ncol * 256 + k];
    }
    const float b1c = f_b1[ncol];
    const float gc = g[ncol];
    __shared__ __align__(16) __bf16 ch_[32 * 256];
    __shared__ float part[8][32];
    const int srow = tid >> 4;
    const int scb = (tid & 15) * 16;
    const bool isagg = scb < 128;
    float4 sc4[4], sh4[4];
    if (isagg) {
#pragma unroll
        for (int q = 0; q < 4; ++q) {
            sc4[q] = *(const float4*)&scale[scb + q * 4];
            sh4[q] = *(const float4*)&shift[scb + q * 4];
        }
    }
    const int nchunks = BN_TOT / 32;
    for (int chk = blockIdx.x; chk < nchunks; chk += gridDim.x) {
        const int row0 = chk * 32;
        {
            const float* srcp = isagg ? (agg + (size_t)(row0 + srow) * D_ + scb)
                                      : (tmat + (size_t)(row0 + srow) * D_ + (scb - 128));
            float v[16];
#pragma unroll
            for (int q = 0; q < 4; ++q) {
                float4 p = *(const float4*)(srcp + q * 4);
                if (isagg) {
                    p.x = fmaxf(p.x * sc4[q].x + sh4[q].x, 0.f);
                    p.y = fmaxf(p.y * sc4[q].y + sh4[q].y, 0.f);
                    p.z = fmaxf(p.z * sc4[q].z + sh4[q].z, 0.f);
                    p.w = fmaxf(p.w * sc4[q].w + sh4[q].w, 0.f);
                }
                v[q * 4 + 0] = p.x; v[q * 4 + 1] = p.y; v[q * 4 + 2] = p.z; v[q * 4 + 3] = p.w;
            }
#pragma unroll
            for (int hh = 0; hh < 2; ++hh) {
                const int c = scb + hh * 8;
                const int idx = srow * 256 + (c ^ ((srow & 7) * 8));
                *(bf16x8*)&ch_[idx] = cvt8(v + hh * 8);
            }
        }
        __syncthreads();
#pragma unroll
        for (int mt = 0; mt < 2; ++mt) {
            f32x4 acc = (f32x4){0.f, 0.f, 0.f, 0.f};
#pragma unroll
            for (int kk = 0; kk < 8; ++kk) {
                const int ai = (mt * 16 + (l & 15)) * 256 + ((kk * 32 + (l >> 4) * 8) ^ ((l & 7) * 8));
                bf16x8 ah = *(const bf16x8*)&ch_[ai];
                acc = __builtin_amdgcn_mfma_f32_16x16x32_bf16(ah, Fh[kk], acc, 0, 0, 0);
                acc = __builtin_amdgcn_mfma_f32_16x16x32_bf16(ah, Fl[kk], acc, 0, 0, 0);
            }
            float p[4];
#pragma unroll
            for (int r = 0; r < 4; ++r) p[r] = fmaxf(acc[r] + b1c, 0.f) * gc;
#pragma unroll
            for (int r = 0; r < 4; ++r) {
                p[r] += __shfl_xor(p[r], 1);
                p[r] += __shfl_xor(p[r], 2);
                p[r] += __shfl_xor(p[r], 4);
                p[r] += __shfl_xor(p[r], 8);
            }
            if ((l & 15) == 0) {
#pragma unroll
                for (int r = 0; r < 4; ++r) part[w][mt * 16 + (l >> 4) * 4 + r] = p[r];
            }
        }
        __syncthreads();
        if (tid < 32) {
            float s = c0v;
#pragma unroll
            for (int ww = 0; ww < 8; ++ww) s += part[ww][tid];
            out[row0 + tid] = s;
        }
        __syncthreads();
    }
}

// ---------------- launch ----------------
extern "C" void kernel_launch(void* const* d_in, const int* in_sizes, int n_in,
                              void* d_out, int out_size, void* d_ws, size_t ws_size,
                              hipStream_t stream) {
    const float* data     = (const float*)d_in[0];
    const int*   ei       = (const int*)d_in[1];
    const float* emb      = (const float*)d_in[2];
    const float* lin_w    = (const float*)d_in[3];
    const float* att_i    = (const float*)d_in[4];
    const float* att_j    = (const float*)d_in[5];
    const float* att_em_i = (const float*)d_in[6];
    const float* att_em_j = (const float*)d_in[7];
    const float* gnn_bias = (const float*)d_in[8];
    const float* bn_gamma = (const float*)d_in[9];
    const float* bn_beta  = (const float*)d_in[10];
    // q_w,q_b,k_w,k_b,temperature dead (W=1 -> softmax over single element -> attn==1)
    const float* v_w      = (const float*)d_in[15];
    const float* v_b      = (const float*)d_in[16];
    const float* f_w1     = (const float*)d_in[18];
    const float* f_b1     = (const float*)d_in[19];
    const float* f_w2     = (const float*)d_in[20];
    const float* f_b2     = (const float*)d_in[21];
    const float* out_w    = (const float*)d_in[22];
    const float* out_b    = (const float*)d_in[23];
    float* out = (float*)d_out;

    float* ws = (float*)d_ws;
    float* x      = ws;                                 // BN*D
    float* tmat   = x + (size_t)BN_TOT * D_;            // BN*D
    float* agg    = tmat + (size_t)BN_TOT * D_;         // BN*D
    float* ni     = agg + (size_t)BN_TOT * D_;          // BN
    float* nj     = ni + BN_TOT;                        // BN
    float* eemi   = nj + BN_TOT;                        // N
    float* eemj   = eemi + N_;                          // N
    float* g      = eemj + N_;                          // D
    float* c0     = g + D_;                             // 1 (pad 8)
    float* scale  = c0 + 8;                             // D
    float* shift  = scale + D_;                         // D
    int* offs     = (int*)(shift + D_);                 // 1024 [zeroed]
    int* cursor   = offs + 1024;                        // 1024 [zeroed]
    float* bn_sum = (float*)(cursor + 1024);            // 128  [zeroed, unused now]
    float* bn_sq  = bn_sum + D_;                        // 128  [zeroed, unused now]
    int* csr_src  = (int*)(bn_sq + D_);                 // E
    float* exbuf  = (float*)(csr_src + E_);             // B*E
    float* selfex = exbuf + (size_t)B_ * E_;            // BN
    float* denomv = selfex + BN_TOT;                    // BN
    __bf16* wcat_h = (__bf16*)(denomv + BN_TOT);        // 256*128
    __bf16* wcat_l = wcat_h + 256 * 128;                // 256*128
    __bf16* f1_h   = wcat_l + 256 * 128;                // 128*256
    __bf16* f1_l   = f1_h + 128 * 256;                  // 128*256
    float* partials = (float*)(f1_l + 128 * 256);       // 1024*256 floats = 1 MB
    unsigned int* xb = (unsigned int*)(partials + 1024 * 256);  // BN*64 uints (packed bf16 x)

    k_zero<<<1, 256, 0, stream>>>(offs);
    k_emb_scores<<<N_, 64, 0, stream>>>(emb, att_em_i, att_em_j, eemi, eemj);
    k_gvec<<<1, 128, 0, stream>>>(f_w2, f_b2, out_w, out_b, g, c0);
    k_wprep<<<256, 256, 0, stream>>>(lin_w, v_w, f_w1, wcat_h, wcat_l, f1_h, f1_l);
    k_mfma_dual<<<1000, 512, 0, stream>>>(data, wcat_h, wcat_l, v_b, x, tmat);
    k_scores<<<BN_TOT / 4, 256, 0, stream>>>(x, att_i, att_j, eemi, eemj, ni, nj, xb);
    k_count<<<(E_ + 255) / 256, 256, 0, stream>>>(ei, offs);
    k_scan<<<1, 1024, 0, stream>>>(offs);
    k_scatter<<<(E_ + 255) / 256, 256, 0, stream>>>(ei, offs, cursor, csr_src);
    k_edge_w<<<BN_TOT / 4, 256, 0, stream>>>(ni, nj, offs, csr_src, exbuf, selfex, denomv);
    k_spmm<<<BN_TOT / 4, 256, 0, stream>>>(xb, offs, csr_src, exbuf, selfex, denomv, gnn_bias, agg);
    k_bn_part<<<1024, 256, 0, stream>>>(agg, partials);
    k_bn_fin2<<<1, 1024, 0, stream>>>(partials, bn_gamma, bn_beta, scale, shift);
    k_mfma_fusion<<<1000, 512, 0, stream>>>(agg, tmat, f1_h, f1_l, f_b1, scale, shift, g, c0, out);
}

// Round 9
// 184.054 us; speedup vs baseline: 1.1358x; 1.1358x over previous
//
#include <hip/hip_runtime.h>
#include <math.h>

constexpr int B_ = 64;
constexpr int N_ = 1000;
constexpr int D_ = 128;
constexpr int E_ = 20000;
constexpr int BN_TOT = B_ * N_;
constexpr float BN_EPS = 1e-5f;
constexpr float NEG_SLOPE = 0.2f;

typedef __attribute__((ext_vector_type(8))) __bf16 bf16x8;
typedef __attribute__((ext_vector_type(4))) float f32x4;
typedef __attribute__((ext_vector_type(2))) float f32x2;

__device__ __forceinline__ float leaky(float a) { return a >= 0.f ? a : NEG_SLOPE * a; }

__device__ __forceinline__ bf16x8 cvt8(const float* v) {
    bf16x8 h;
#pragma unroll
    for (int j = 0; j < 8; ++j) h[j] = (__bf16)v[j];
    return h;
}

// ---------------- merged prep: wprep | zero | gvec | emb_scores ----------------
__global__ __launch_bounds__(256) void k_prep(const float* __restrict__ lin_w,
                                              const float* __restrict__ v_w,
                                              const float* __restrict__ f_w1,
                                              const float* __restrict__ emb,
                                              const float* __restrict__ att_em_i,
                                              const float* __restrict__ att_em_j,
                                              const float* __restrict__ f_w2,
                                              const float* __restrict__ f_b2,
                                              const float* __restrict__ out_w,
                                              const float* __restrict__ out_b,
                                              __bf16* __restrict__ wcat_h, __bf16* __restrict__ wcat_l,
                                              __bf16* __restrict__ f1_h, __bf16* __restrict__ f1_l,
                                              float* __restrict__ eemi, float* __restrict__ eemj,
                                              float* __restrict__ g, float* __restrict__ c0,
                                              int* __restrict__ zbase) {
    const int blk = blockIdx.x;
    const int tid = threadIdx.x;
    if (blk < 256) {            // weight split bf16 hi/lo
        int i = blk * 256 + tid;
        if (i < 32768) {
            float v = (i < 16384) ? lin_w[i] : v_w[i - 16384];
            __bf16 h = (__bf16)v;
            wcat_h[i] = h;
            wcat_l[i] = (__bf16)(v - (float)h);
        } else {
            int j = i - 32768;
            float v = f_w1[j];
            __bf16 h = (__bf16)v;
            f1_h[j] = h;
            f1_l[j] = (__bf16)(v - (float)h);
        }
    } else if (blk == 256) {    // zero counters
        for (int k = tid; k < 2304; k += 256) zbase[k] = 0;
    } else if (blk == 257) {    // g vector + c0
        if (tid < 128) {
            float s = 0.f;
            for (int k = 0; k < D_; ++k) s += out_w[k] * f_w2[k * D_ + tid];
            g[tid] = s;
            if (tid == 0) {
                float c = out_b[0];
                for (int k = 0; k < D_; ++k) c += out_w[k] * f_b2[k];
                *c0 = c;
            }
        }
    } else {                    // emb scores: blocks 258..507, 4 nodes each
        const int wid = tid >> 6;
        const int lane = tid & 63;
        const int n = (blk - 258) * 4 + wid;
        const float* er = emb + (size_t)n * D_;
        float e0 = er[lane], e1 = er[lane + 64];
        float si = e0 * att_em_i[lane] + e1 * att_em_i[lane + 64];
        float sj = e0 * att_em_j[lane] + e1 * att_em_j[lane + 64];
        for (int off = 32; off > 0; off >>= 1) {
            si += __shfl_down(si, off);
            sj += __shfl_down(sj, off);
        }
        if (lane == 0) { eemi[n] = si; eemj[n] = sj; }
    }
}

// ---------------- MFMA dual GEMM, double-buffered prefetch ----------------
// [x | t] = data @ [lin_w ; v_w]^T (+v_b on t half). A bf16-hi; weights hi+lo.
// Pipeline: issue chunk n+1 global loads -> barrier -> MFMA on buf[cur] ->
// epilogue -> write prefetched regs to buf[cur^1]. One barrier/chunk:
// iter-i reads of buf[cur] and iter-i+1 writes of buf[cur] are separated by
// iter-i+1's barrier.
__global__ __launch_bounds__(512) void k_mfma_dual(const float* __restrict__ data,
                                                   const __bf16* __restrict__ wcat_h,
                                                   const __bf16* __restrict__ wcat_l,
                                                   const float* __restrict__ v_b,
                                                   float* __restrict__ x,
                                                   float* __restrict__ tmat) {
    const int tid = threadIdx.x;
    const int w = tid >> 6;
    const int l = tid & 63;
    bf16x8 Bh[2][4], Bl[2][4];
#pragma unroll
    for (int nt = 0; nt < 2; ++nt) {
        const int n = w * 32 + nt * 16 + (l & 15);
#pragma unroll
        for (int kk = 0; kk < 4; ++kk) {
            const int k = kk * 32 + (l >> 4) * 8;
            Bh[nt][kk] = *(const bf16x8*)&wcat_h[n * D_ + k];
            Bl[nt][kk] = *(const bf16x8*)&wcat_l[n * D_ + k];
        }
    }
    float vb[2] = {0.f, 0.f};
    if (w >= 4) {
#pragma unroll
        for (int nt = 0; nt < 2; ++nt) vb[nt] = v_b[w * 32 + nt * 16 + (l & 15) - 128];
    }
    __shared__ __align__(16) __bf16 dh[2][32 * D_];
    const int srow = tid >> 4;
    const int skq = (tid & 15) * 8;
    const int soff = srow * D_ + (skq ^ ((srow & 7) * 8));
    const int nchunks = BN_TOT / 32;
    float4 q0, q1;
    {   // prologue: chunk blockIdx.x into buf 0
        const float* src = data + (size_t)(blockIdx.x * 32 + srow) * D_ + skq;
        q0 = *(const float4*)src;
        q1 = *(const float4*)(src + 4);
        float v[8] = {q0.x, q0.y, q0.z, q0.w, q1.x, q1.y, q1.z, q1.w};
        *(bf16x8*)&dh[0][soff] = cvt8(v);
    }
    int cur = 0;
    for (int ch = blockIdx.x; ch < nchunks; ch += gridDim.x) {
        const int nxt = ch + gridDim.x;
        if (nxt < nchunks) {    // issue next chunk's loads (latency hidden under MFMA)
            const float* src = data + (size_t)(nxt * 32 + srow) * D_ + skq;
            q0 = *(const float4*)src;
            q1 = *(const float4*)(src + 4);
        }
        __syncthreads();        // buf[cur] writes visible; prior readers of buf[cur^1] done
        f32x4 acc[2][2];
#pragma unroll
        for (int mt = 0; mt < 2; ++mt)
#pragma unroll
            for (int nt = 0; nt < 2; ++nt) acc[mt][nt] = (f32x4){0.f, 0.f, 0.f, 0.f};
#pragma unroll
        for (int mt = 0; mt < 2; ++mt) {
#pragma unroll
            for (int kk = 0; kk < 4; ++kk) {
                const int ai = (mt * 16 + (l & 15)) * D_ + ((kk * 32 + (l >> 4) * 8) ^ ((l & 7) * 8));
                bf16x8 ah = *(const bf16x8*)&dh[cur][ai];
#pragma unroll
                for (int nt = 0; nt < 2; ++nt) {
                    acc[mt][nt] = __builtin_amdgcn_mfma_f32_16x16x32_bf16(ah, Bh[nt][kk], acc[mt][nt], 0, 0, 0);
                    acc[mt][nt] = __builtin_amdgcn_mfma_f32_16x16x32_bf16(ah, Bl[nt][kk], acc[mt][nt], 0, 0, 0);
                }
            }
        }
        const int row0 = ch * 32;
#pragma unroll
        for (int mt = 0; mt < 2; ++mt) {
#pragma unroll
            for (int nt = 0; nt < 2; ++nt) {
                const int col = w * 32 + nt * 16 + (l & 15);
                const int rg = row0 + mt * 16 + (l >> 4) * 4;
                if (w < 4) {
#pragma unroll
                    for (int r = 0; r < 4; ++r)
                        x[(size_t)(rg + r) * D_ + col] = acc[mt][nt][r];
                } else {
                    const int c2 = col - 128;
#pragma unroll
                    for (int r = 0; r < 4; ++r)
                        tmat[(size_t)(rg + r) * D_ + c2] = acc[mt][nt][r] + vb[nt];
                }
            }
        }
        if (nxt < nchunks) {    // write prefetched chunk to the other buffer
            float v[8] = {q0.x, q0.y, q0.z, q0.w, q1.x, q1.y, q1.z, q1.w};
            *(bf16x8*)&dh[cur ^ 1][soff] = cvt8(v);
        }
        cur ^= 1;
    }
}

// ---------------- node attention scores + packed-bf16 x copy ----------------
__global__ __launch_bounds__(256) void k_scores(const float* __restrict__ x,
                                                const float* __restrict__ att_i,
                                                const float* __restrict__ att_j,
                                                const float* __restrict__ eemi,
                                                const float* __restrict__ eemj,
                                                float* __restrict__ ni, float* __restrict__ nj,
                                                unsigned int* __restrict__ xb) {
    const int wid = threadIdx.x >> 6;
    const int lane = threadIdx.x & 63;
    const int row = blockIdx.x * 4 + wid;
    f32x2 xv = ((const f32x2*)x)[(size_t)row * 64 + lane];
    f32x2 ai = ((const f32x2*)att_i)[lane];
    f32x2 aj = ((const f32x2*)att_j)[lane];
    float si = xv.x * ai.x + xv.y * ai.y;
    float sj = xv.x * aj.x + xv.y * aj.y;
    {
        __bf16 bx = (__bf16)xv.x, by = (__bf16)xv.y;
        unsigned int ux = *(const unsigned short*)&bx;
        unsigned int uy = *(const unsigned short*)&by;
        xb[(size_t)row * 64 + lane] = ux | (uy << 16);
    }
    for (int off = 32; off > 0; off >>= 1) {
        si += __shfl_down(si, off);
        sj += __shfl_down(sj, off);
    }
    if (lane == 0) {
        int n = row % N_;
        ni[row] = si + eemi[n];
        nj[row] = sj + eemj[n];
    }
}

// ---------------- CSR build ----------------
__global__ void k_count(const int* __restrict__ ei, int* __restrict__ offs) {
    int e = blockIdx.x * blockDim.x + threadIdx.x;
    if (e < E_) atomicAdd(&offs[ei[E_ + e] + 1], 1);
}

__global__ __launch_bounds__(1024) void k_scan(int* __restrict__ offs) {
    __shared__ int s[N_ + 1];
    int tid = threadIdx.x;
    if (tid <= N_) s[tid] = offs[tid];
    __syncthreads();
    for (int off = 1; off <= N_; off <<= 1) {
        int v = 0;
        if (tid <= N_) { v = s[tid]; if (tid >= off) v += s[tid - off]; }
        __syncthreads();
        if (tid <= N_) s[tid] = v;
        __syncthreads();
    }
    if (tid <= N_) offs[tid] = s[tid];
}

__global__ void k_scatter(const int* __restrict__ ei, const int* __restrict__ offs,
                          int* __restrict__ cursor, int* __restrict__ csr_src) {
    int e = blockIdx.x * blockDim.x + threadIdx.x;
    if (e < E_) {
        int dn = ei[E_ + e];
        int pos = offs[dn] + atomicAdd(&cursor[dn], 1);
        csr_src[pos] = ei[e];
    }
}

// ---------------- edge softmax: one WAVE per (b,i) ----------------
__global__ __launch_bounds__(256) void k_edge_w(const float* __restrict__ ni,
                                                const float* __restrict__ nj,
                                                const int* __restrict__ offs,
                                                const int* __restrict__ csr_src,
                                                float* __restrict__ exbuf,
                                                float* __restrict__ selfex,
                                                float* __restrict__ denomv) {
    const int wid = threadIdx.x >> 6;
    const int lane = threadIdx.x & 63;
    const int bid = blockIdx.x * 4 + wid;
    const int b = bid / N_;
    const int i = bid - b * N_;
    const int base = b * N_;
    const int e0 = offs[i], e1 = offs[i + 1];
    const float nii = ni[bid];
    const float aself = leaky(nii + nj[bid]);
    float amax = aself;
    for (int e = e0 + lane; e < e1; e += 64) {
        int s = csr_src[e];
        amax = fmaxf(amax, leaky(nii + nj[base + s]));
    }
    for (int off = 32; off > 0; off >>= 1) amax = fmaxf(amax, __shfl_xor(amax, off));
    float sum = 0.f;
    if (lane == 0) {
        float se = __expf(aself - amax);
        selfex[bid] = se;
        sum = se;
    }
    for (int e = e0 + lane; e < e1; e += 64) {
        int s = csr_src[e];
        float ex = __expf(leaky(nii + nj[base + s]) - amax);
        exbuf[(size_t)b * E_ + e] = ex;
        sum += ex;
    }
    for (int off = 32; off > 0; off >>= 1) sum += __shfl_xor(sum, off);
    if (lane == 0) denomv[bid] = sum;
}

// ---------------- SpMM gather-aggregate: wave/segment, bf16 payload, NT agg store ----------
__global__ __launch_bounds__(256) void k_spmm(const unsigned int* __restrict__ xb,
                                              const int* __restrict__ offs,
                                              const int* __restrict__ csr_src,
                                              const float* __restrict__ exbuf,
                                              const float* __restrict__ selfex,
                                              const float* __restrict__ denomv,
                                              const float* __restrict__ gnn_bias,
                                              float* __restrict__ agg) {
    constexpr int CAP = 128;
    __shared__ int s_lds[4][CAP];
    __shared__ float w_lds[4][CAP];
    const int swz = (blockIdx.x & 7) * 2000 + (blockIdx.x >> 3);
    const int w = threadIdx.x >> 6;
    const int l = threadIdx.x & 63;
    const int bid = swz * 4 + w;
    const int b = bid / N_;
    const int i = bid - b * N_;
    const int base = b * N_;
    const int e0 = offs[i];
    const int deg = offs[i + 1] - e0;
    const int stg = deg < CAP ? deg : CAP;
    for (int k = l; k < stg; k += 64) {
        s_lds[w][k] = csr_src[e0 + k];
        w_lds[w][k] = exbuf[(size_t)b * E_ + e0 + k];
    }
    __syncthreads();
    float accx, accy;
    {
        float se = selfex[bid];
        unsigned int u = xb[(size_t)bid * 64 + l];
        accx = se * __uint_as_float(u << 16);
        accy = se * __uint_as_float(u & 0xffff0000u);
    }
    int k = 0;
    for (; k + 8 <= stg; k += 8) {
        unsigned int u[8];
        float wg[8];
#pragma unroll
        for (int j = 0; j < 8; ++j) {
            int s = s_lds[w][k + j];
            wg[j] = w_lds[w][k + j];
            u[j] = xb[(size_t)(base + s) * 64 + l];
        }
#pragma unroll
        for (int j = 0; j < 8; ++j) {
            accx += wg[j] * __uint_as_float(u[j] << 16);
            accy += wg[j] * __uint_as_float(u[j] & 0xffff0000u);
        }
    }
    for (; k < stg; ++k) {
        int s = s_lds[w][k];
        float wg = w_lds[w][k];
        unsigned int u = xb[(size_t)(base + s) * 64 + l];
        accx += wg * __uint_as_float(u << 16);
        accy += wg * __uint_as_float(u & 0xffff0000u);
    }
    for (int e = e0 + CAP; e < e0 + deg; ++e) {
        int s = csr_src[e];
        float wg = exbuf[(size_t)b * E_ + e];
        unsigned int u = xb[(size_t)(base + s) * 64 + l];
        accx += wg * __uint_as_float(u << 16);
        accy += wg * __uint_as_float(u & 0xffff0000u);
    }
    const float dn = 1.f / denomv[bid];
    f32x2 gb = ((const f32x2*)gnn_bias)[l];
    f32x2 o;
    o.x = accx * dn + gb.x;
    o.y = accy * dn + gb.y;
    __builtin_nontemporal_store(o, (f32x2*)agg + (size_t)bid * 64 + l);
}

// ---------------- BatchNorm statistics: two-stage ----------------
__global__ __launch_bounds__(256) void k_bn_part(const float* __restrict__ agg,
                                                 float* __restrict__ partials) {
    const int g = threadIdx.x >> 5;
    const int c4 = threadIdx.x & 31;
    f32x4 s = (f32x4){0.f, 0.f, 0.f, 0.f};
    f32x4 q = (f32x4){0.f, 0.f, 0.f, 0.f};
    for (int r = blockIdx.x * 8 + g; r < BN_TOT; r += 8192) {
        float4 v = *(const float4*)&agg[(size_t)r * D_ + c4 * 4];
        s.x += v.x; s.y += v.y; s.z += v.z; s.w += v.w;
        q.x += v.x * v.x; q.y += v.y * v.y; q.z += v.z * v.z; q.w += v.w * v.w;
    }
    __shared__ f32x4 ls[8][32];
    __shared__ f32x4 lq[8][32];
    ls[g][c4] = s;
    lq[g][c4] = q;
    __syncthreads();
    if (threadIdx.x < 32) {
        f32x4 ts = ls[0][threadIdx.x];
        f32x4 tq = lq[0][threadIdx.x];
#pragma unroll
        for (int gg = 1; gg < 8; ++gg) {
            f32x4 a = ls[gg][threadIdx.x];
            f32x4 b = lq[gg][threadIdx.x];
            ts.x += a.x; ts.y += a.y; ts.z += a.z; ts.w += a.w;
            tq.x += b.x; tq.y += b.y; tq.z += b.z; tq.w += b.w;
        }
        f32x4* p = (f32x4*)partials + (size_t)blockIdx.x * 64;
        p[threadIdx.x] = ts;
        p[32 + threadIdx.x] = tq;
    }
}

__global__ __launch_bounds__(1024) void k_bn_fin2(const float* __restrict__ partials,
                                                  const float* __restrict__ gamma,
                                                  const float* __restrict__ beta,
                                                  float* __restrict__ scale,
                                                  float* __restrict__ shift) {
    const int d = threadIdx.x & 127;
    const int part = threadIdx.x >> 7;
    float s = 0.f, q = 0.f;
    for (int blk = part * 128; blk < part * 128 + 128; ++blk) {
        s += partials[(size_t)blk * 256 + d];
        q += partials[(size_t)blk * 256 + 128 + d];
    }
    __shared__ float lss[8][128];
    __shared__ float lqq[8][128];
    lss[part][d] = s;
    lqq[part][d] = q;
    __syncthreads();
    if (threadIdx.x < 128) {
        float ts = 0.f, tq = 0.f;
#pragma unroll
        for (int p = 0; p < 8; ++p) { ts += lss[p][d]; tq += lqq[p][d]; }
        float mu = ts * (1.f / BN_TOT);
        float var = tq * (1.f / BN_TOT) - mu * mu;
        float sc = gamma[d] * rsqrtf(var + BN_EPS);
        scale[d] = sc;
        shift[d] = beta[d] - mu * sc;
    }
}

// ---------------- MFMA fusion, double-buffered prefetch ----------------
// out[r] = g . relu(f_w1 @ [bnrelu(agg[r]) | t[r]] + b1) + c0
__global__ __launch_bounds__(512) void k_mfma_fusion(const float* __restrict__ agg,
                                                     const float* __restrict__ tmat,
                                                     const __bf16* __restrict__ f1_h,
                                                     const __bf16* __restrict__ f1_l,
                                                     const float* __restrict__ f_b1,
                                                     const float* __restrict__ scale,
                                                     const float* __restrict__ shift,
                                                     const float* __restrict__ g,
                                                     const float* __restrict__ c0p,
                                                     float* __restrict__ out) {
    const int tid = threadIdx.x;
    const int w = tid >> 6;
    const int l = tid & 63;
    const float c0v = *c0p;
    bf16x8 Fh[8], Fl[8];
    const int ncol = w * 16 + (l & 15);
#pragma unroll
    for (int kk = 0; kk < 8; ++kk) {
        const int k = kk * 32 + (l >> 4) * 8;
        Fh[kk] = *(const bf16x8*)&f1_h[ncol * 256 + k];
        Fl[kk] = *(const bf16x8*)&f1_l[ncol * 256 + k];
    }
    const float b1c = f_b1[ncol];
    const float gc = g[ncol];
    __shared__ __align__(16) __bf16 ch_[2][32 * 256];
    __shared__ float part[8][32];
    const int srow = tid >> 4;
    const int scb = (tid & 15) * 16;
    const bool isagg = scb < 128;
    float4 sc4[4], sh4[4];
    if (isagg) {
#pragma unroll
        for (int q = 0; q < 4; ++q) {
            sc4[q] = *(const float4*)&scale[scb + q * 4];
            sh4[q] = *(const float4*)&shift[scb + q * 4];
        }
    }
    const int nchunks = BN_TOT / 32;
    float4 q[4];
    auto loadc = [&](int chk) {
        const float* srcp = isagg ? (agg + (size_t)(chk * 32 + srow) * D_ + scb)
                                  : (tmat + (size_t)(chk * 32 + srow) * D_ + (scb - 128));
#pragma unroll
        for (int qq = 0; qq < 4; ++qq) q[qq] = *(const float4*)(srcp + qq * 4);
    };
    auto storec = [&](int buf) {
        float v[16];
#pragma unroll
        for (int qq = 0; qq < 4; ++qq) {
            float4 p = q[qq];
            if (isagg) {
                p.x = fmaxf(p.x * sc4[qq].x + sh4[qq].x, 0.f);
                p.y = fmaxf(p.y * sc4[qq].y + sh4[qq].y, 0.f);
                p.z = fmaxf(p.z * sc4[qq].z + sh4[qq].z, 0.f);
                p.w = fmaxf(p.w * sc4[qq].w + sh4[qq].w, 0.f);
            }
            v[qq * 4 + 0] = p.x; v[qq * 4 + 1] = p.y; v[qq * 4 + 2] = p.z; v[qq * 4 + 3] = p.w;
        }
#pragma unroll
        for (int hh = 0; hh < 2; ++hh) {
            const int c = scb + hh * 8;
            const int idx = srow * 256 + (c ^ ((srow & 7) * 8));
            *(bf16x8*)&ch_[buf][idx] = cvt8(v + hh * 8);
        }
    };
    loadc(blockIdx.x);
    storec(0);
    int cur = 0;
    for (int chk = blockIdx.x; chk < nchunks; chk += gridDim.x) {
        const int nxt = chk + gridDim.x;
        if (nxt < nchunks) loadc(nxt);   // issue early; waitcnt lands at storec below
        __syncthreads();                 // (A) buf[cur] visible; part free
#pragma unroll
        for (int mt = 0; mt < 2; ++mt) {
            f32x4 acc = (f32x4){0.f, 0.f, 0.f, 0.f};
#pragma unroll
            for (int kk = 0; kk < 8; ++kk) {
                const int ai = (mt * 16 + (l & 15)) * 256 + ((kk * 32 + (l >> 4) * 8) ^ ((l & 7) * 8));
                bf16x8 ah = *(const bf16x8*)&ch_[cur][ai];
                acc = __builtin_amdgcn_mfma_f32_16x16x32_bf16(ah, Fh[kk], acc, 0, 0, 0);
                acc = __builtin_amdgcn_mfma_f32_16x16x32_bf16(ah, Fl[kk], acc, 0, 0, 0);
            }
            float p[4];
#pragma unroll
            for (int r = 0; r < 4; ++r) p[r] = fmaxf(acc[r] + b1c, 0.f) * gc;
#pragma unroll
            for (int r = 0; r < 4; ++r) {
                p[r] += __shfl_xor(p[r], 1);
                p[r] += __shfl_xor(p[r], 2);
                p[r] += __shfl_xor(p[r], 4);
                p[r] += __shfl_xor(p[r], 8);
            }
            if ((l & 15) == 0) {
#pragma unroll
                for (int r = 0; r < 4; ++r) part[w][mt * 16 + (l >> 4) * 4 + r] = p[r];
            }
        }
        __syncthreads();                 // (B) part ready; all reads of buf[cur] done
        if (tid < 32) {
            float s = c0v;
#pragma unroll
            for (int ww = 0; ww < 8; ++ww) s += part[ww][tid];
            out[chk * 32 + tid] = s;
        }
        if (nxt < nchunks) storec(cur ^ 1);  // buf[cur^1] readers finished in iter i-1
        cur ^= 1;
    }
}

// ---------------- launch ----------------
extern "C" void kernel_launch(void* const* d_in, const int* in_sizes, int n_in,
                              void* d_out, int out_size, void* d_ws, size_t ws_size,
                              hipStream_t stream) {
    const float* data     = (const float*)d_in[0];
    const int*   ei       = (const int*)d_in[1];
    const float* emb      = (const float*)d_in[2];
    const float* lin_w    = (const float*)d_in[3];
    const float* att_i    = (const float*)d_in[4];
    const float* att_j    = (const float*)d_in[5];
    const float* att_em_i = (const float*)d_in[6];
    const float* att_em_j = (const float*)d_in[7];
    const float* gnn_bias = (const float*)d_in[8];
    const float* bn_gamma = (const float*)d_in[9];
    const float* bn_beta  = (const float*)d_in[10];
    // q_w,q_b,k_w,k_b,temperature dead (W=1 -> softmax over single element -> attn==1)
    const float* v_w      = (const float*)d_in[15];
    const float* v_b      = (const float*)d_in[16];
    const float* f_w1     = (const float*)d_in[18];
    const float* f_b1     = (const float*)d_in[19];
    const float* f_w2     = (const float*)d_in[20];
    const float* f_b2     = (const float*)d_in[21];
    const float* out_w    = (const float*)d_in[22];
    const float* out_b    = (const float*)d_in[23];
    float* out = (float*)d_out;

    float* ws = (float*)d_ws;
    float* x      = ws;                                 // BN*D
    float* tmat   = x + (size_t)BN_TOT * D_;            // BN*D
    float* agg    = tmat + (size_t)BN_TOT * D_;         // BN*D
    float* ni     = agg + (size_t)BN_TOT * D_;          // BN
    float* nj     = ni + BN_TOT;                        // BN
    float* eemi   = nj + BN_TOT;                        // N
    float* eemj   = eemi + N_;                          // N
    float* g      = eemj + N_;                          // D
    float* c0     = g + D_;                             // 1 (pad 8)
    float* scale  = c0 + 8;                             // D
    float* shift  = scale + D_;                         // D
    int* offs     = (int*)(shift + D_);                 // 1024 [zeroed]
    int* cursor   = offs + 1024;                        // 1024 [zeroed]
    float* bn_sum = (float*)(cursor + 1024);            // 128  [zeroed, unused]
    float* bn_sq  = bn_sum + D_;                        // 128  [zeroed, unused]
    int* csr_src  = (int*)(bn_sq + D_);                 // E
    float* exbuf  = (float*)(csr_src + E_);             // B*E
    float* selfex = exbuf + (size_t)B_ * E_;            // BN
    float* denomv = selfex + BN_TOT;                    // BN
    __bf16* wcat_h = (__bf16*)(denomv + BN_TOT);        // 256*128
    __bf16* wcat_l = wcat_h + 256 * 128;                // 256*128
    __bf16* f1_h   = wcat_l + 256 * 128;                // 128*256
    __bf16* f1_l   = f1_h + 128 * 256;                  // 128*256
    float* partials = (float*)(f1_l + 128 * 256);       // 1024*256 floats = 1 MB
    unsigned int* xb = (unsigned int*)(partials + 1024 * 256);  // BN*64 uints

    k_prep<<<508, 256, 0, stream>>>(lin_w, v_w, f_w1, emb, att_em_i, att_em_j,
                                    f_w2, f_b2, out_w, out_b,
                                    wcat_h, wcat_l, f1_h, f1_l,
                                    eemi, eemj, g, c0, offs);
    k_mfma_dual<<<500, 512, 0, stream>>>(data, wcat_h, wcat_l, v_b, x, tmat);
    k_scores<<<BN_TOT / 4, 256, 0, stream>>>(x, att_i, att_j, eemi, eemj, ni, nj, xb);
    k_count<<<(E_ + 255) / 256, 256, 0, stream>>>(ei, offs);
    k_scan<<<1, 1024, 0, stream>>>(offs);
    k_scatter<<<(E_ + 255) / 256, 256, 0, stream>>>(ei, offs, cursor, csr_src);
    k_edge_w<<<BN_TOT / 4, 256, 0, stream>>>(ni, nj, offs, csr_src, exbuf, selfex, denomv);
    k_spmm<<<BN_TOT / 4, 256, 0, stream>>>(xb, offs, csr_src, exbuf, selfex, denomv, gnn_bias, agg);
    k_bn_part<<<1024, 256, 0, stream>>>(agg, partials);
    k_bn_fin2<<<1, 1024, 0, stream>>>(partials, bn_gamma, bn_beta, scale, shift);
    k_mfma_fusion<<<500, 512, 0, stream>>>(agg, tmat, f1_h, f1_l, f_b1, scale, shift, g, c0, out);
}

// Round 10
// 169.142 us; speedup vs baseline: 1.2360x; 1.0882x over previous
//
#include <hip/hip_runtime.h>
#include <math.h>

constexpr int B_ = 64;
constexpr int N_ = 1000;
constexpr int D_ = 128;
constexpr int E_ = 20000;
constexpr int BN_TOT = B_ * N_;
constexpr float BN_EPS = 1e-5f;
constexpr float NEG_SLOPE = 0.2f;

typedef __attribute__((ext_vector_type(8))) __bf16 bf16x8;
typedef __attribute__((ext_vector_type(4))) float f32x4;
typedef __attribute__((ext_vector_type(2))) float f32x2;

__device__ __forceinline__ float leaky(float a) { return a >= 0.f ? a : NEG_SLOPE * a; }

__device__ __forceinline__ bf16x8 cvt8(const float* v) {
    bf16x8 h;
#pragma unroll
    for (int j = 0; j < 8; ++j) h[j] = (__bf16)v[j];
    return h;
}

// ---------------- merged prep: wprep | zero | gvec | emb_scores ----------------
__global__ __launch_bounds__(256) void k_prep(const float* __restrict__ lin_w,
                                              const float* __restrict__ v_w,
                                              const float* __restrict__ f_w1,
                                              const float* __restrict__ emb,
                                              const float* __restrict__ att_em_i,
                                              const float* __restrict__ att_em_j,
                                              const float* __restrict__ f_w2,
                                              const float* __restrict__ f_b2,
                                              const float* __restrict__ out_w,
                                              const float* __restrict__ out_b,
                                              __bf16* __restrict__ wcat_h, __bf16* __restrict__ wcat_l,
                                              __bf16* __restrict__ f1_h, __bf16* __restrict__ f1_l,
                                              float* __restrict__ eemi, float* __restrict__ eemj,
                                              float* __restrict__ g, float* __restrict__ c0,
                                              int* __restrict__ zbase) {
    const int blk = blockIdx.x;
    const int tid = threadIdx.x;
    if (blk < 256) {            // weight split bf16 hi/lo
        int i = blk * 256 + tid;
        if (i < 32768) {
            float v = (i < 16384) ? lin_w[i] : v_w[i - 16384];
            __bf16 h = (__bf16)v;
            wcat_h[i] = h;
            wcat_l[i] = (__bf16)(v - (float)h);
        } else {
            int j = i - 32768;
            float v = f_w1[j];
            __bf16 h = (__bf16)v;
            f1_h[j] = h;
            f1_l[j] = (__bf16)(v - (float)h);
        }
    } else if (blk == 256) {    // zero counters
        for (int k = tid; k < 2304; k += 256) zbase[k] = 0;
    } else if (blk == 257) {    // g vector + c0
        if (tid < 128) {
            float s = 0.f;
            for (int k = 0; k < D_; ++k) s += out_w[k] * f_w2[k * D_ + tid];
            g[tid] = s;
            if (tid == 0) {
                float c = out_b[0];
                for (int k = 0; k < D_; ++k) c += out_w[k] * f_b2[k];
                *c0 = c;
            }
        }
    } else {                    // emb scores: blocks 258..507, 4 nodes each
        const int wid = tid >> 6;
        const int lane = tid & 63;
        const int n = (blk - 258) * 4 + wid;
        const float* er = emb + (size_t)n * D_;
        float e0 = er[lane], e1 = er[lane + 64];
        float si = e0 * att_em_i[lane] + e1 * att_em_i[lane + 64];
        float sj = e0 * att_em_j[lane] + e1 * att_em_j[lane + 64];
        for (int off = 32; off > 0; off >>= 1) {
            si += __shfl_down(si, off);
            sj += __shfl_down(sj, off);
        }
        if (lane == 0) { eemi[n] = si; eemj[n] = sj; }
    }
}

// ---------------- CSR build ----------------
__global__ void k_count(const int* __restrict__ ei, int* __restrict__ offs) {
    int e = blockIdx.x * blockDim.x + threadIdx.x;
    if (e < E_) atomicAdd(&offs[ei[E_ + e] + 1], 1);
}

__global__ __launch_bounds__(1024) void k_scan(int* __restrict__ offs) {
    __shared__ int s[N_ + 1];
    int tid = threadIdx.x;
    if (tid <= N_) s[tid] = offs[tid];
    __syncthreads();
    for (int off = 1; off <= N_; off <<= 1) {
        int v = 0;
        if (tid <= N_) { v = s[tid]; if (tid >= off) v += s[tid - off]; }
        __syncthreads();
        if (tid <= N_) s[tid] = v;
        __syncthreads();
    }
    if (tid <= N_) offs[tid] = s[tid];
}

__global__ void k_scatter(const int* __restrict__ ei, const int* __restrict__ offs,
                          int* __restrict__ cursor, int* __restrict__ csr_src) {
    int e = blockIdx.x * blockDim.x + threadIdx.x;
    if (e < E_) {
        int dn = ei[E_ + e];
        int pos = offs[dn] + atomicAdd(&cursor[dn], 1);
        csr_src[pos] = ei[e];
    }
}

// ---------------- MFMA dual GEMM + fused scores/xb-pack, double-buffered ----------------
// [x | t] = data @ [lin_w ; v_w]^T (+v_b). Epilogue also computes
// ni/nj (per-row x·att dot via shfl+LDS reduce) and packed-bf16 xb.
__global__ __launch_bounds__(512) void k_mfma_dual(const float* __restrict__ data,
                                                   const __bf16* __restrict__ wcat_h,
                                                   const __bf16* __restrict__ wcat_l,
                                                   const float* __restrict__ v_b,
                                                   const float* __restrict__ att_i,
                                                   const float* __restrict__ att_j,
                                                   const float* __restrict__ eemi,
                                                   const float* __restrict__ eemj,
                                                   float* __restrict__ x,
                                                   float* __restrict__ tmat,
                                                   float* __restrict__ ni,
                                                   float* __restrict__ nj,
                                                   unsigned int* __restrict__ xb) {
    const int tid = threadIdx.x;
    const int w = tid >> 6;
    const int l = tid & 63;
    bf16x8 Bh[2][4], Bl[2][4];
#pragma unroll
    for (int nt = 0; nt < 2; ++nt) {
        const int n = w * 32 + nt * 16 + (l & 15);
#pragma unroll
        for (int kk = 0; kk < 4; ++kk) {
            const int k = kk * 32 + (l >> 4) * 8;
            Bh[nt][kk] = *(const bf16x8*)&wcat_h[n * D_ + k];
            Bl[nt][kk] = *(const bf16x8*)&wcat_l[n * D_ + k];
        }
    }
    float vb[2] = {0.f, 0.f};
    float ai[2] = {0.f, 0.f}, aj[2] = {0.f, 0.f};
    if (w >= 4) {
#pragma unroll
        for (int nt = 0; nt < 2; ++nt) vb[nt] = v_b[w * 32 + nt * 16 + (l & 15) - 128];
    } else {
#pragma unroll
        for (int nt = 0; nt < 2; ++nt) {
            const int col = w * 32 + nt * 16 + (l & 15);
            ai[nt] = att_i[col];
            aj[nt] = att_j[col];
        }
    }
    __shared__ __align__(16) __bf16 dh[2][32 * D_];
    __shared__ float sred_i[4][32];
    __shared__ float sred_j[4][32];
    const int srow = tid >> 4;
    const int skq = (tid & 15) * 8;
    const int soff = srow * D_ + (skq ^ ((srow & 7) * 8));
    const int nchunks = BN_TOT / 32;
    float4 q0, q1;
    {   // prologue: chunk blockIdx.x into buf 0
        const float* src = data + (size_t)(blockIdx.x * 32 + srow) * D_ + skq;
        q0 = *(const float4*)src;
        q1 = *(const float4*)(src + 4);
        float v[8] = {q0.x, q0.y, q0.z, q0.w, q1.x, q1.y, q1.z, q1.w};
        *(bf16x8*)&dh[0][soff] = cvt8(v);
    }
    int cur = 0;
    for (int ch = blockIdx.x; ch < nchunks; ch += gridDim.x) {
        const int nxt = ch + gridDim.x;
        if (nxt < nchunks) {    // issue next chunk's loads (hidden under MFMA)
            const float* src = data + (size_t)(nxt * 32 + srow) * D_ + skq;
            q0 = *(const float4*)src;
            q1 = *(const float4*)(src + 4);
        }
        __syncthreads();        // (A) buf[cur] visible
        f32x4 acc[2][2];
#pragma unroll
        for (int mt = 0; mt < 2; ++mt)
#pragma unroll
            for (int nt = 0; nt < 2; ++nt) acc[mt][nt] = (f32x4){0.f, 0.f, 0.f, 0.f};
#pragma unroll
        for (int mt = 0; mt < 2; ++mt) {
#pragma unroll
            for (int kk = 0; kk < 4; ++kk) {
                const int aidx = (mt * 16 + (l & 15)) * D_ + ((kk * 32 + (l >> 4) * 8) ^ ((l & 7) * 8));
                bf16x8 ah = *(const bf16x8*)&dh[cur][aidx];
#pragma unroll
                for (int nt = 0; nt < 2; ++nt) {
                    acc[mt][nt] = __builtin_amdgcn_mfma_f32_16x16x32_bf16(ah, Bh[nt][kk], acc[mt][nt], 0, 0, 0);
                    acc[mt][nt] = __builtin_amdgcn_mfma_f32_16x16x32_bf16(ah, Bl[nt][kk], acc[mt][nt], 0, 0, 0);
                }
            }
        }
        const int row0 = ch * 32;
        float pi[8], pj[8];
#pragma unroll
        for (int k2 = 0; k2 < 8; ++k2) { pi[k2] = 0.f; pj[k2] = 0.f; }
#pragma unroll
        for (int mt = 0; mt < 2; ++mt) {
#pragma unroll
            for (int nt = 0; nt < 2; ++nt) {
                const int col = w * 32 + nt * 16 + (l & 15);
                const int rg = row0 + mt * 16 + (l >> 4) * 4;
                if (w < 4) {
#pragma unroll
                    for (int r = 0; r < 4; ++r) {
                        float v = acc[mt][nt][r];
                        x[(size_t)(rg + r) * D_ + col] = v;
                        pi[mt * 4 + r] += v * ai[nt];
                        pj[mt * 4 + r] += v * aj[nt];
                    }
                } else {
                    const int c2 = col - 128;
#pragma unroll
                    for (int r = 0; r < 4; ++r)
                        tmat[(size_t)(rg + r) * D_ + c2] = acc[mt][nt][r] + vb[nt];
                }
            }
        }
        if (w < 4) {
            // packed-bf16 xb: pair adjacent cols via lane^1 shuffle
#pragma unroll
            for (int mt = 0; mt < 2; ++mt) {
#pragma unroll
                for (int nt = 0; nt < 2; ++nt) {
#pragma unroll
                    for (int r = 0; r < 4; ++r) {
                        float v = acc[mt][nt][r];
                        float vp = __shfl_xor(v, 1);
                        if (!(l & 1)) {
                            __bf16 b0 = (__bf16)v, b1 = (__bf16)vp;
                            unsigned int u0 = *(const unsigned short*)&b0;
                            unsigned int u1 = *(const unsigned short*)&b1;
                            const int row = row0 + mt * 16 + (l >> 4) * 4 + r;
                            xb[(size_t)row * 64 + ((w * 32 + nt * 16 + (l & 15)) >> 1)] = u0 | (u1 << 16);
                        }
                    }
                }
            }
            // per-row score partials: reduce over the 16-lane col group
#pragma unroll
            for (int off = 1; off < 16; off <<= 1) {
#pragma unroll
                for (int k2 = 0; k2 < 8; ++k2) {
                    pi[k2] += __shfl_xor(pi[k2], off);
                    pj[k2] += __shfl_xor(pj[k2], off);
                }
            }
            if ((l & 15) == 0) {
#pragma unroll
                for (int mt = 0; mt < 2; ++mt)
#pragma unroll
                    for (int r = 0; r < 4; ++r) {
                        sred_i[w][mt * 16 + (l >> 4) * 4 + r] = pi[mt * 4 + r];
                        sred_j[w][mt * 16 + (l >> 4) * 4 + r] = pj[mt * 4 + r];
                    }
            }
        }
        __syncthreads();        // (B) sred visible; all dh[cur] reads done
        if (tid < 32) {
            const int row = row0 + tid;
            float si = sred_i[0][tid] + sred_i[1][tid] + sred_i[2][tid] + sred_i[3][tid];
            float sj = sred_j[0][tid] + sred_j[1][tid] + sred_j[2][tid] + sred_j[3][tid];
            const int n = row % N_;
            ni[row] = si + eemi[n];
            nj[row] = sj + eemj[n];
        }
        if (nxt < nchunks) {    // write prefetched chunk to the other buffer
            float v[8] = {q0.x, q0.y, q0.z, q0.w, q1.x, q1.y, q1.z, q1.w};
            *(bf16x8*)&dh[cur ^ 1][soff] = cvt8(v);
        }
        cur ^= 1;
    }
}

// ---------------- fused edge softmax + SpMM: wave per segment ----------------
// Phase 1 (lanes=edges): leaky/max/exp/denominator into LDS, no global staging.
// Phase 2 (lanes=channels): bf16 gather + FMA, NT agg store.
__global__ __launch_bounds__(256) void k_sagg(const unsigned int* __restrict__ xb,
                                              const int* __restrict__ offs,
                                              const int* __restrict__ csr_src,
                                              const float* __restrict__ ni,
                                              const float* __restrict__ nj,
                                              const float* __restrict__ gnn_bias,
                                              float* __restrict__ agg) {
    constexpr int CAP = 128;
    __shared__ int s_lds[4][CAP];
    __shared__ float w_lds[4][CAP];
    const int swz = (blockIdx.x & 7) * 2000 + (blockIdx.x >> 3);
    const int w = threadIdx.x >> 6;
    const int l = threadIdx.x & 63;
    const int bid = swz * 4 + w;
    const int b = bid / N_;
    const int i = bid - b * N_;
    const int base = b * N_;
    const int e0 = offs[i];
    const int deg = offs[i + 1] - e0;
    const int stg = deg < CAP ? deg : CAP;
    const float nii = ni[bid];
    const float aself = leaky(nii + nj[bid]);
    // phase 1: lanes over edges (deg <= 128 covered by 2 slots/lane)
    float aa0 = -1e30f, aa1 = -1e30f;
    if (l < stg) {
        int s = csr_src[e0 + l];
        s_lds[w][l] = s;
        aa0 = leaky(nii + nj[base + s]);
    }
    if (l + 64 < stg) {
        int s = csr_src[e0 + l + 64];
        s_lds[w][l + 64] = s;
        aa1 = leaky(nii + nj[base + s]);
    }
    float amax = fmaxf(aself, fmaxf(aa0, aa1));
    for (int e = e0 + CAP + l; e < e0 + deg; e += 64)
        amax = fmaxf(amax, leaky(nii + nj[base + csr_src[e]]));
    for (int off = 32; off > 0; off >>= 1) amax = fmaxf(amax, __shfl_xor(amax, off));
    const float se = __expf(aself - amax);   // uniform across wave
    float sum = 0.f;
    if (l < stg) { float ex = __expf(aa0 - amax); w_lds[w][l] = ex; sum += ex; }
    if (l + 64 < stg) { float ex = __expf(aa1 - amax); w_lds[w][l + 64] = ex; sum += ex; }
    for (int off = 32; off > 0; off >>= 1) sum += __shfl_xor(sum, off);
    float denom = se + sum;
    __syncthreads();   // cheap insurance for cross-lane LDS visibility
    // phase 2: lanes over channels
    float accx, accy;
    {
        unsigned int u = xb[(size_t)bid * 64 + l];
        accx = se * __uint_as_float(u << 16);
        accy = se * __uint_as_float(u & 0xffff0000u);
    }
    int k = 0;
    for (; k + 8 <= stg; k += 8) {
        unsigned int u[8];
        float wg[8];
#pragma unroll
        for (int j = 0; j < 8; ++j) {
            int s = s_lds[w][k + j];
            wg[j] = w_lds[w][k + j];
            u[j] = xb[(size_t)(base + s) * 64 + l];
        }
#pragma unroll
        for (int j = 0; j < 8; ++j) {
            accx += wg[j] * __uint_as_float(u[j] << 16);
            accy += wg[j] * __uint_as_float(u[j] & 0xffff0000u);
        }
    }
    for (; k < stg; ++k) {
        int s = s_lds[w][k];
        float wg = w_lds[w][k];
        unsigned int u = xb[(size_t)(base + s) * 64 + l];
        accx += wg * __uint_as_float(u << 16);
        accy += wg * __uint_as_float(u & 0xffff0000u);
    }
    for (int e = e0 + CAP; e < e0 + deg; ++e) {   // overflow fallback (recompute, uniform)
        int s = csr_src[e];
        float wg = __expf(leaky(nii + nj[base + s]) - amax);
        unsigned int u = xb[(size_t)(base + s) * 64 + l];
        accx += wg * __uint_as_float(u << 16);
        accy += wg * __uint_as_float(u & 0xffff0000u);
        denom += wg;
    }
    const float dn = 1.f / denom;
    f32x2 gb = ((const f32x2*)gnn_bias)[l];
    f32x2 o;
    o.x = accx * dn + gb.x;
    o.y = accy * dn + gb.y;
    __builtin_nontemporal_store(o, (f32x2*)agg + (size_t)bid * 64 + l);
}

// ---------------- BatchNorm statistics: two-stage ----------------
__global__ __launch_bounds__(256) void k_bn_part(const float* __restrict__ agg,
                                                 float* __restrict__ partials) {
    const int g = threadIdx.x >> 5;
    const int c4 = threadIdx.x & 31;
    f32x4 s = (f32x4){0.f, 0.f, 0.f, 0.f};
    f32x4 q = (f32x4){0.f, 0.f, 0.f, 0.f};
    for (int r = blockIdx.x * 8 + g; r < BN_TOT; r += 8192) {
        float4 v = *(const float4*)&agg[(size_t)r * D_ + c4 * 4];
        s.x += v.x; s.y += v.y; s.z += v.z; s.w += v.w;
        q.x += v.x * v.x; q.y += v.y * v.y; q.z += v.z * v.z; q.w += v.w * v.w;
    }
    __shared__ f32x4 ls[8][32];
    __shared__ f32x4 lq[8][32];
    ls[g][c4] = s;
    lq[g][c4] = q;
    __syncthreads();
    if (threadIdx.x < 32) {
        f32x4 ts = ls[0][threadIdx.x];
        f32x4 tq = lq[0][threadIdx.x];
#pragma unroll
        for (int gg = 1; gg < 8; ++gg) {
            f32x4 a = ls[gg][threadIdx.x];
            f32x4 b = lq[gg][threadIdx.x];
            ts.x += a.x; ts.y += a.y; ts.z += a.z; ts.w += a.w;
            tq.x += b.x; tq.y += b.y; tq.z += b.z; tq.w += b.w;
        }
        f32x4* p = (f32x4*)partials + (size_t)blockIdx.x * 64;
        p[threadIdx.x] = ts;
        p[32 + threadIdx.x] = tq;
    }
}

__global__ __launch_bounds__(1024) void k_bn_fin2(const float* __restrict__ partials,
                                                  const float* __restrict__ gamma,
                                                  const float* __restrict__ beta,
                                                  float* __restrict__ scale,
                                                  float* __restrict__ shift) {
    const int d = threadIdx.x & 127;
    const int part = threadIdx.x >> 7;
    float s = 0.f, q = 0.f;
    for (int blk = part * 128; blk < part * 128 + 128; ++blk) {
        s += partials[(size_t)blk * 256 + d];
        q += partials[(size_t)blk * 256 + 128 + d];
    }
    __shared__ float lss[8][128];
    __shared__ float lqq[8][128];
    lss[part][d] = s;
    lqq[part][d] = q;
    __syncthreads();
    if (threadIdx.x < 128) {
        float ts = 0.f, tq = 0.f;
#pragma unroll
        for (int p = 0; p < 8; ++p) { ts += lss[p][d]; tq += lqq[p][d]; }
        float mu = ts * (1.f / BN_TOT);
        float var = tq * (1.f / BN_TOT) - mu * mu;
        float sc = gamma[d] * rsqrtf(var + BN_EPS);
        scale[d] = sc;
        shift[d] = beta[d] - mu * sc;
    }
}

// ---------------- MFMA fusion, double-buffered prefetch ----------------
__global__ __launch_bounds__(512) void k_mfma_fusion(const float* __restrict__ agg,
                                                     const float* __restrict__ tmat,
                                                     const __bf16* __restrict__ f1_h,
                                                     const __bf16* __restrict__ f1_l,
                                                     const float* __restrict__ f_b1,
                                                     const float* __restrict__ scale,
                                                     const float* __restrict__ shift,
                                                     const float* __restrict__ g,
                                                     const float* __restrict__ c0p,
                                                     float* __restrict__ out) {
    const int tid = threadIdx.x;
    const int w = tid >> 6;
    const int l = tid & 63;
    const float c0v = *c0p;
    bf16x8 Fh[8], Fl[8];
    const int ncol = w * 16 + (l & 15);
#pragma unroll
    for (int kk = 0; kk < 8; ++kk) {
        const int k = kk * 32 + (l >> 4) * 8;
        Fh[kk] = *(const bf16x8*)&f1_h[ncol * 256 + k];
        Fl[kk] = *(const bf16x8*)&f1_l[ncol * 256 + k];
    }
    const float b1c = f_b1[ncol];
    const float gc = g[ncol];
    __shared__ __align__(16) __bf16 ch_[2][32 * 256];
    __shared__ float part[8][32];
    const int srow = tid >> 4;
    const int scb = (tid & 15) * 16;
    const bool isagg = scb < 128;
    float4 sc4[4], sh4[4];
    if (isagg) {
#pragma unroll
        for (int q = 0; q < 4; ++q) {
            sc4[q] = *(const float4*)&scale[scb + q * 4];
            sh4[q] = *(const float4*)&shift[scb + q * 4];
        }
    }
    const int nchunks = BN_TOT / 32;
    float4 q[4];
    auto loadc = [&](int chk) {
        const float* srcp = isagg ? (agg + (size_t)(chk * 32 + srow) * D_ + scb)
                                  : (tmat + (size_t)(chk * 32 + srow) * D_ + (scb - 128));
#pragma unroll
        for (int qq = 0; qq < 4; ++qq) q[qq] = *(const float4*)(srcp + qq * 4);
    };
    auto storec = [&](int buf) {
        float v[16];
#pragma unroll
        for (int qq = 0; qq < 4; ++qq) {
            float4 p = q[qq];
            if (isagg) {
                p.x = fmaxf(p.x * sc4[qq].x + sh4[qq].x, 0.f);
                p.y = fmaxf(p.y * sc4[qq].y + sh4[qq].y, 0.f);
                p.z = fmaxf(p.z * sc4[qq].z + sh4[qq].z, 0.f);
                p.w = fmaxf(p.w * sc4[qq].w + sh4[qq].w, 0.f);
            }
            v[qq * 4 + 0] = p.x; v[qq * 4 + 1] = p.y; v[qq * 4 + 2] = p.z; v[qq * 4 + 3] = p.w;
        }
#pragma unroll
        for (int hh = 0; hh < 2; ++hh) {
            const int c = scb + hh * 8;
            const int idx = srow * 256 + (c ^ ((srow & 7) * 8));
            *(bf16x8*)&ch_[buf][idx] = cvt8(v + hh * 8);
        }
    };
    loadc(blockIdx.x);
    storec(0);
    int cur = 0;
    for (int chk = blockIdx.x; chk < nchunks; chk += gridDim.x) {
        const int nxt = chk + gridDim.x;
        if (nxt < nchunks) loadc(nxt);
        __syncthreads();                 // (A) buf[cur] visible; part free
#pragma unroll
        for (int mt = 0; mt < 2; ++mt) {
            f32x4 acc = (f32x4){0.f, 0.f, 0.f, 0.f};
#pragma unroll
            for (int kk = 0; kk < 8; ++kk) {
                const int ai = (mt * 16 + (l & 15)) * 256 + ((kk * 32 + (l >> 4) * 8) ^ ((l & 7) * 8));
                bf16x8 ah = *(const bf16x8*)&ch_[cur][ai];
                acc = __builtin_amdgcn_mfma_f32_16x16x32_bf16(ah, Fh[kk], acc, 0, 0, 0);
                acc = __builtin_amdgcn_mfma_f32_16x16x32_bf16(ah, Fl[kk], acc, 0, 0, 0);
            }
            float p[4];
#pragma unroll
            for (int r = 0; r < 4; ++r) p[r] = fmaxf(acc[r] + b1c, 0.f) * gc;
#pragma unroll
            for (int r = 0; r < 4; ++r) {
                p[r] += __shfl_xor(p[r], 1);
                p[r] += __shfl_xor(p[r], 2);
                p[r] += __shfl_xor(p[r], 4);
                p[r] += __shfl_xor(p[r], 8);
            }
            if ((l & 15) == 0) {
#pragma unroll
                for (int r = 0; r < 4; ++r) part[w][mt * 16 + (l >> 4) * 4 + r] = p[r];
            }
        }
        __syncthreads();                 // (B) part ready; buf[cur] reads done
        if (tid < 32) {
            float s = c0v;
#pragma unroll
            for (int ww = 0; ww < 8; ++ww) s += part[ww][tid];
            out[chk * 32 + tid] = s;
        }
        if (nxt < nchunks) storec(cur ^ 1);
        cur ^= 1;
    }
}

// ---------------- launch ----------------
extern "C" void kernel_launch(void* const* d_in, const int* in_sizes, int n_in,
                              void* d_out, int out_size, void* d_ws, size_t ws_size,
                              hipStream_t stream) {
    const float* data     = (const float*)d_in[0];
    const int*   ei       = (const int*)d_in[1];
    const float* emb      = (const float*)d_in[2];
    const float* lin_w    = (const float*)d_in[3];
    const float* att_i    = (const float*)d_in[4];
    const float* att_j    = (const float*)d_in[5];
    const float* att_em_i = (const float*)d_in[6];
    const float* att_em_j = (const float*)d_in[7];
    const float* gnn_bias = (const float*)d_in[8];
    const float* bn_gamma = (const float*)d_in[9];
    const float* bn_beta  = (const float*)d_in[10];
    // q_w,q_b,k_w,k_b,temperature dead (W=1 -> softmax over single element -> attn==1)
    const float* v_w      = (const float*)d_in[15];
    const float* v_b      = (const float*)d_in[16];
    const float* f_w1     = (const float*)d_in[18];
    const float* f_b1     = (const float*)d_in[19];
    const float* f_w2     = (const float*)d_in[20];
    const float* f_b2     = (const float*)d_in[21];
    const float* out_w    = (const float*)d_in[22];
    const float* out_b    = (const float*)d_in[23];
    float* out = (float*)d_out;

    float* ws = (float*)d_ws;
    float* x      = ws;                                 // BN*D
    float* tmat   = x + (size_t)BN_TOT * D_;            // BN*D
    float* agg    = tmat + (size_t)BN_TOT * D_;         // BN*D
    float* ni     = agg + (size_t)BN_TOT * D_;          // BN
    float* nj     = ni + BN_TOT;                        // BN
    float* eemi   = nj + BN_TOT;                        // N
    float* eemj   = eemi + N_;                          // N
    float* g      = eemj + N_;                          // D
    float* c0     = g + D_;                             // 1 (pad 8)
    float* scale  = c0 + 8;                             // D
    float* shift  = scale + D_;                         // D
    int* offs     = (int*)(shift + D_);                 // 1024 [zeroed]
    int* cursor   = offs + 1024;                        // 1024 [zeroed]
    float* bn_sum = (float*)(cursor + 1024);            // 128  [zeroed, unused]
    float* bn_sq  = bn_sum + D_;                        // 128  [zeroed, unused]
    int* csr_src  = (int*)(bn_sq + D_);                 // E
    float* exbuf  = (float*)(csr_src + E_);             // B*E (unused now, layout kept)
    float* selfex = exbuf + (size_t)B_ * E_;            // BN (unused)
    float* denomv = selfex + BN_TOT;                    // BN (unused)
    __bf16* wcat_h = (__bf16*)(denomv + BN_TOT);        // 256*128
    __bf16* wcat_l = wcat_h + 256 * 128;                // 256*128
    __bf16* f1_h   = wcat_l + 256 * 128;                // 128*256
    __bf16* f1_l   = f1_h + 128 * 256;                  // 128*256
    float* partials = (float*)(f1_l + 128 * 256);       // 1024*256 floats = 1 MB
    unsigned int* xb = (unsigned int*)(partials + 1024 * 256);  // BN*64 uints

    k_prep<<<508, 256, 0, stream>>>(lin_w, v_w, f_w1, emb, att_em_i, att_em_j,
                                    f_w2, f_b2, out_w, out_b,
                                    wcat_h, wcat_l, f1_h, f1_l,
                                    eemi, eemj, g, c0, offs);
    k_count<<<(E_ + 255) / 256, 256, 0, stream>>>(ei, offs);
    k_scan<<<1, 1024, 0, stream>>>(offs);
    k_scatter<<<(E_ + 255) / 256, 256, 0, stream>>>(ei, offs, cursor, csr_src);
    k_mfma_dual<<<500, 512, 0, stream>>>(data, wcat_h, wcat_l, v_b,
                                         att_i, att_j, eemi, eemj,
                                         x, tmat, ni, nj, xb);
    k_sagg<<<BN_TOT / 4, 256, 0, stream>>>(xb, offs, csr_src, ni, nj, gnn_bias, agg);
    k_bn_part<<<1024, 256, 0, stream>>>(agg, partials);
    k_bn_fin2<<<1, 1024, 0, stream>>>(partials, bn_gamma, bn_beta, scale, shift);
    k_mfma_fusion<<<500, 512, 0, stream>>>(agg, tmat, f1_h, f1_l, f_b1, scale, shift, g, c0, out);
}

// Round 11
// 164.304 us; speedup vs baseline: 1.2724x; 1.0294x over previous
//
#include <hip/hip_runtime.h>
#include <math.h>

constexpr int B_ = 64;
constexpr int N_ = 1000;
constexpr int D_ = 128;
constexpr int E_ = 20000;
constexpr int BN_TOT = B_ * N_;
constexpr float BN_EPS = 1e-5f;
constexpr float NEG_SLOPE = 0.2f;

typedef __attribute__((ext_vector_type(8))) __bf16 bf16x8;
typedef __attribute__((ext_vector_type(4))) float f32x4;
typedef __attribute__((ext_vector_type(2))) float f32x2;

__device__ __forceinline__ float leaky(float a) { return a >= 0.f ? a : NEG_SLOPE * a; }

__device__ __forceinline__ bf16x8 cvt8(const float* v) {
    bf16x8 h;
#pragma unroll
    for (int j = 0; j < 8; ++j) h[j] = (__bf16)v[j];
    return h;
}

__device__ __forceinline__ unsigned int packpair(float v, int l) {
    float vp = __shfl_xor(v, 1);
    __bf16 b0 = (__bf16)v, b1 = (__bf16)vp;
    unsigned int u0 = *(const unsigned short*)&b0;
    unsigned int u1 = *(const unsigned short*)&b1;
    return u0 | (u1 << 16);   // valid on even lanes: (col, col+1) row-major bf16
}

// ---------------- merged prep: wprep | zero | gvec | emb_scores ----------------
__global__ __launch_bounds__(256) void k_prep(const float* __restrict__ lin_w,
                                              const float* __restrict__ v_w,
                                              const float* __restrict__ f_w1,
                                              const float* __restrict__ emb,
                                              const float* __restrict__ att_em_i,
                                              const float* __restrict__ att_em_j,
                                              const float* __restrict__ f_w2,
                                              const float* __restrict__ f_b2,
                                              const float* __restrict__ out_w,
                                              const float* __restrict__ out_b,
                                              __bf16* __restrict__ wcat_h, __bf16* __restrict__ wcat_l,
                                              __bf16* __restrict__ f1_h, __bf16* __restrict__ f1_l,
                                              float* __restrict__ eemi, float* __restrict__ eemj,
                                              float* __restrict__ g, float* __restrict__ c0,
                                              int* __restrict__ zbase) {
    const int blk = blockIdx.x;
    const int tid = threadIdx.x;
    if (blk < 256) {            // weight split bf16 hi/lo
        int i = blk * 256 + tid;
        if (i < 32768) {
            float v = (i < 16384) ? lin_w[i] : v_w[i - 16384];
            __bf16 h = (__bf16)v;
            wcat_h[i] = h;
            wcat_l[i] = (__bf16)(v - (float)h);
        } else {
            int j = i - 32768;
            float v = f_w1[j];
            __bf16 h = (__bf16)v;
            f1_h[j] = h;
            f1_l[j] = (__bf16)(v - (float)h);
        }
    } else if (blk == 256) {    // zero counters
        for (int k = tid; k < 2304; k += 256) zbase[k] = 0;
    } else if (blk == 257) {    // g vector + c0
        if (tid < 128) {
            float s = 0.f;
            for (int k = 0; k < D_; ++k) s += out_w[k] * f_w2[k * D_ + tid];
            g[tid] = s;
            if (tid == 0) {
                float c = out_b[0];
                for (int k = 0; k < D_; ++k) c += out_w[k] * f_b2[k];
                *c0 = c;
            }
        }
    } else {                    // emb scores: blocks 258..507, 4 nodes each
        const int wid = tid >> 6;
        const int lane = tid & 63;
        const int n = (blk - 258) * 4 + wid;
        const float* er = emb + (size_t)n * D_;
        float e0 = er[lane], e1 = er[lane + 64];
        float si = e0 * att_em_i[lane] + e1 * att_em_i[lane + 64];
        float sj = e0 * att_em_j[lane] + e1 * att_em_j[lane + 64];
        for (int off = 32; off > 0; off >>= 1) {
            si += __shfl_down(si, off);
            sj += __shfl_down(sj, off);
        }
        if (lane == 0) { eemi[n] = si; eemj[n] = sj; }
    }
}

// ---------------- CSR build ----------------
__global__ void k_count(const int* __restrict__ ei, int* __restrict__ offs) {
    int e = blockIdx.x * blockDim.x + threadIdx.x;
    if (e < E_) atomicAdd(&offs[ei[E_ + e] + 1], 1);
}

__global__ __launch_bounds__(1024) void k_scan(int* __restrict__ offs) {
    __shared__ int s[N_ + 1];
    int tid = threadIdx.x;
    if (tid <= N_) s[tid] = offs[tid];
    __syncthreads();
    for (int off = 1; off <= N_; off <<= 1) {
        int v = 0;
        if (tid <= N_) { v = s[tid]; if (tid >= off) v += s[tid - off]; }
        __syncthreads();
        if (tid <= N_) s[tid] = v;
        __syncthreads();
    }
    if (tid <= N_) offs[tid] = s[tid];
}

__global__ void k_scatter(const int* __restrict__ ei, const int* __restrict__ offs,
                          int* __restrict__ cursor, int* __restrict__ csr_src) {
    int e = blockIdx.x * blockDim.x + threadIdx.x;
    if (e < E_) {
        int dn = ei[E_ + e];
        int pos = offs[dn] + atomicAdd(&cursor[dn], 1);
        csr_src[pos] = ei[e];
    }
}

// ---------------- MFMA dual GEMM + fused scores, bf16-only outputs ----------------
// Outputs: xb (packed bf16 x), tb (packed bf16 t), ni/nj. fp32 x/tmat never hit HBM.
__global__ __launch_bounds__(512) void k_mfma_dual(const float* __restrict__ data,
                                                   const __bf16* __restrict__ wcat_h,
                                                   const __bf16* __restrict__ wcat_l,
                                                   const float* __restrict__ v_b,
                                                   const float* __restrict__ att_i,
                                                   const float* __restrict__ att_j,
                                                   const float* __restrict__ eemi,
                                                   const float* __restrict__ eemj,
                                                   float* __restrict__ ni,
                                                   float* __restrict__ nj,
                                                   unsigned int* __restrict__ xb,
                                                   unsigned int* __restrict__ tb) {
    const int tid = threadIdx.x;
    const int w = tid >> 6;
    const int l = tid & 63;
    bf16x8 Bh[2][4], Bl[2][4];
#pragma unroll
    for (int nt = 0; nt < 2; ++nt) {
        const int n = w * 32 + nt * 16 + (l & 15);
#pragma unroll
        for (int kk = 0; kk < 4; ++kk) {
            const int k = kk * 32 + (l >> 4) * 8;
            Bh[nt][kk] = *(const bf16x8*)&wcat_h[n * D_ + k];
            Bl[nt][kk] = *(const bf16x8*)&wcat_l[n * D_ + k];
        }
    }
    float vb[2] = {0.f, 0.f};
    float ai[2] = {0.f, 0.f}, aj[2] = {0.f, 0.f};
    if (w >= 4) {
#pragma unroll
        for (int nt = 0; nt < 2; ++nt) vb[nt] = v_b[w * 32 + nt * 16 + (l & 15) - 128];
    } else {
#pragma unroll
        for (int nt = 0; nt < 2; ++nt) {
            const int col = w * 32 + nt * 16 + (l & 15);
            ai[nt] = att_i[col];
            aj[nt] = att_j[col];
        }
    }
    __shared__ __align__(16) __bf16 dh[2][32 * D_];
    __shared__ float sred_i[4][32];
    __shared__ float sred_j[4][32];
    const int srow = tid >> 4;
    const int skq = (tid & 15) * 8;
    const int soff = srow * D_ + (skq ^ ((srow & 7) * 8));
    const int nchunks = BN_TOT / 32;
    float4 q0, q1;
    {   // prologue: chunk blockIdx.x into buf 0
        const float* src = data + (size_t)(blockIdx.x * 32 + srow) * D_ + skq;
        q0 = *(const float4*)src;
        q1 = *(const float4*)(src + 4);
        float v[8] = {q0.x, q0.y, q0.z, q0.w, q1.x, q1.y, q1.z, q1.w};
        *(bf16x8*)&dh[0][soff] = cvt8(v);
    }
    int cur = 0;
    for (int ch = blockIdx.x; ch < nchunks; ch += gridDim.x) {
        const int nxt = ch + gridDim.x;
        if (nxt < nchunks) {    // issue next chunk's loads (hidden under MFMA)
            const float* src = data + (size_t)(nxt * 32 + srow) * D_ + skq;
            q0 = *(const float4*)src;
            q1 = *(const float4*)(src + 4);
        }
        __syncthreads();        // (A) buf[cur] visible
        f32x4 acc[2][2];
#pragma unroll
        for (int mt = 0; mt < 2; ++mt)
#pragma unroll
            for (int nt = 0; nt < 2; ++nt) acc[mt][nt] = (f32x4){0.f, 0.f, 0.f, 0.f};
#pragma unroll
        for (int mt = 0; mt < 2; ++mt) {
#pragma unroll
            for (int kk = 0; kk < 4; ++kk) {
                const int aidx = (mt * 16 + (l & 15)) * D_ + ((kk * 32 + (l >> 4) * 8) ^ ((l & 7) * 8));
                bf16x8 ah = *(const bf16x8*)&dh[cur][aidx];
#pragma unroll
                for (int nt = 0; nt < 2; ++nt) {
                    acc[mt][nt] = __builtin_amdgcn_mfma_f32_16x16x32_bf16(ah, Bh[nt][kk], acc[mt][nt], 0, 0, 0);
                    acc[mt][nt] = __builtin_amdgcn_mfma_f32_16x16x32_bf16(ah, Bl[nt][kk], acc[mt][nt], 0, 0, 0);
                }
            }
        }
        const int row0 = ch * 32;
        if (w < 4) {
            float pi[8], pj[8];
#pragma unroll
            for (int k2 = 0; k2 < 8; ++k2) { pi[k2] = 0.f; pj[k2] = 0.f; }
#pragma unroll
            for (int mt = 0; mt < 2; ++mt) {
#pragma unroll
                for (int nt = 0; nt < 2; ++nt) {
                    const int col = w * 32 + nt * 16 + (l & 15);
#pragma unroll
                    for (int r = 0; r < 4; ++r) {
                        float v = acc[mt][nt][r];
                        pi[mt * 4 + r] += v * ai[nt];
                        pj[mt * 4 + r] += v * aj[nt];
                        unsigned int u = packpair(v, l);
                        if (!(l & 1)) {
                            const int row = row0 + mt * 16 + (l >> 4) * 4 + r;
                            xb[(size_t)row * 64 + (col >> 1)] = u;
                        }
                    }
                }
            }
            // per-row score partials: reduce over the 16-lane col group
#pragma unroll
            for (int off = 1; off < 16; off <<= 1) {
#pragma unroll
                for (int k2 = 0; k2 < 8; ++k2) {
                    pi[k2] += __shfl_xor(pi[k2], off);
                    pj[k2] += __shfl_xor(pj[k2], off);
                }
            }
            if ((l & 15) == 0) {
#pragma unroll
                for (int mt = 0; mt < 2; ++mt)
#pragma unroll
                    for (int r = 0; r < 4; ++r) {
                        sred_i[w][mt * 16 + (l >> 4) * 4 + r] = pi[mt * 4 + r];
                        sred_j[w][mt * 16 + (l >> 4) * 4 + r] = pj[mt * 4 + r];
                    }
            }
        } else {
#pragma unroll
            for (int mt = 0; mt < 2; ++mt) {
#pragma unroll
                for (int nt = 0; nt < 2; ++nt) {
                    const int c2 = w * 32 + nt * 16 + (l & 15) - 128;
#pragma unroll
                    for (int r = 0; r < 4; ++r) {
                        float v = acc[mt][nt][r] + vb[nt];
                        unsigned int u = packpair(v, l);
                        if (!(l & 1)) {
                            const int row = row0 + mt * 16 + (l >> 4) * 4 + r;
                            tb[(size_t)row * 64 + (c2 >> 1)] = u;
                        }
                    }
                }
            }
        }
        __syncthreads();        // (B) sred visible; all dh[cur] reads done
        if (tid < 32) {
            const int row = row0 + tid;
            float si = sred_i[0][tid] + sred_i[1][tid] + sred_i[2][tid] + sred_i[3][tid];
            float sj = sred_j[0][tid] + sred_j[1][tid] + sred_j[2][tid] + sred_j[3][tid];
            const int n = row % N_;
            ni[row] = si + eemi[n];
            nj[row] = sj + eemj[n];
        }
        if (nxt < nchunks) {    // write prefetched chunk to the other buffer
            float v[8] = {q0.x, q0.y, q0.z, q0.w, q1.x, q1.y, q1.z, q1.w};
            *(bf16x8*)&dh[cur ^ 1][soff] = cvt8(v);
        }
        cur ^= 1;
    }
}

// ---------------- fused edge softmax + SpMM: wave per segment ----------------
__global__ __launch_bounds__(256) void k_sagg(const unsigned int* __restrict__ xb,
                                              const int* __restrict__ offs,
                                              const int* __restrict__ csr_src,
                                              const float* __restrict__ ni,
                                              const float* __restrict__ nj,
                                              const float* __restrict__ gnn_bias,
                                              float* __restrict__ agg) {
    constexpr int CAP = 128;
    __shared__ int s_lds[4][CAP];
    __shared__ float w_lds[4][CAP];
    const int swz = (blockIdx.x & 7) * 2000 + (blockIdx.x >> 3);
    const int w = threadIdx.x >> 6;
    const int l = threadIdx.x & 63;
    const int bid = swz * 4 + w;
    const int b = bid / N_;
    const int i = bid - b * N_;
    const int base = b * N_;
    const int e0 = offs[i];
    const int deg = offs[i + 1] - e0;
    const int stg = deg < CAP ? deg : CAP;
    const float nii = ni[bid];
    const float aself = leaky(nii + nj[bid]);
    // phase 1: lanes over edges
    float aa0 = -1e30f, aa1 = -1e30f;
    if (l < stg) {
        int s = csr_src[e0 + l];
        s_lds[w][l] = s;
        aa0 = leaky(nii + nj[base + s]);
    }
    if (l + 64 < stg) {
        int s = csr_src[e0 + l + 64];
        s_lds[w][l + 64] = s;
        aa1 = leaky(nii + nj[base + s]);
    }
    float amax = fmaxf(aself, fmaxf(aa0, aa1));
    for (int e = e0 + CAP + l; e < e0 + deg; e += 64)
        amax = fmaxf(amax, leaky(nii + nj[base + csr_src[e]]));
    for (int off = 32; off > 0; off >>= 1) amax = fmaxf(amax, __shfl_xor(amax, off));
    const float se = __expf(aself - amax);
    float sum = 0.f;
    if (l < stg) { float ex = __expf(aa0 - amax); w_lds[w][l] = ex; sum += ex; }
    if (l + 64 < stg) { float ex = __expf(aa1 - amax); w_lds[w][l + 64] = ex; sum += ex; }
    for (int off = 32; off > 0; off >>= 1) sum += __shfl_xor(sum, off);
    float denom = se + sum;
    __syncthreads();
    // phase 2: lanes over channels
    float accx, accy;
    {
        unsigned int u = xb[(size_t)bid * 64 + l];
        accx = se * __uint_as_float(u << 16);
        accy = se * __uint_as_float(u & 0xffff0000u);
    }
    int k = 0;
    for (; k + 8 <= stg; k += 8) {
        unsigned int u[8];
        float wg[8];
#pragma unroll
        for (int j = 0; j < 8; ++j) {
            int s = s_lds[w][k + j];
            wg[j] = w_lds[w][k + j];
            u[j] = xb[(size_t)(base + s) * 64 + l];
        }
#pragma unroll
        for (int j = 0; j < 8; ++j) {
            accx += wg[j] * __uint_as_float(u[j] << 16);
            accy += wg[j] * __uint_as_float(u[j] & 0xffff0000u);
        }
    }
    for (; k < stg; ++k) {
        int s = s_lds[w][k];
        float wg = w_lds[w][k];
        unsigned int u = xb[(size_t)(base + s) * 64 + l];
        accx += wg * __uint_as_float(u << 16);
        accy += wg * __uint_as_float(u & 0xffff0000u);
    }
    for (int e = e0 + CAP; e < e0 + deg; ++e) {
        int s = csr_src[e];
        float wg = __expf(leaky(nii + nj[base + s]) - amax);
        unsigned int u = xb[(size_t)(base + s) * 64 + l];
        accx += wg * __uint_as_float(u << 16);
        accy += wg * __uint_as_float(u & 0xffff0000u);
        denom += wg;
    }
    const float dn = 1.f / denom;
    f32x2 gb = ((const f32x2*)gnn_bias)[l];
    f32x2 o;
    o.x = accx * dn + gb.x;
    o.y = accy * dn + gb.y;
    __builtin_nontemporal_store(o, (f32x2*)agg + (size_t)bid * 64 + l);
}

// ---------------- BatchNorm statistics: two-stage ----------------
__global__ __launch_bounds__(256) void k_bn_part(const float* __restrict__ agg,
                                                 float* __restrict__ partials) {
    const int g = threadIdx.x >> 5;
    const int c4 = threadIdx.x & 31;
    f32x4 s = (f32x4){0.f, 0.f, 0.f, 0.f};
    f32x4 q = (f32x4){0.f, 0.f, 0.f, 0.f};
    for (int r = blockIdx.x * 8 + g; r < BN_TOT; r += 8192) {
        float4 v = *(const float4*)&agg[(size_t)r * D_ + c4 * 4];
        s.x += v.x; s.y += v.y; s.z += v.z; s.w += v.w;
        q.x += v.x * v.x; q.y += v.y * v.y; q.z += v.z * v.z; q.w += v.w * v.w;
    }
    __shared__ f32x4 ls[8][32];
    __shared__ f32x4 lq[8][32];
    ls[g][c4] = s;
    lq[g][c4] = q;
    __syncthreads();
    if (threadIdx.x < 32) {
        f32x4 ts = ls[0][threadIdx.x];
        f32x4 tq = lq[0][threadIdx.x];
#pragma unroll
        for (int gg = 1; gg < 8; ++gg) {
            f32x4 a = ls[gg][threadIdx.x];
            f32x4 b = lq[gg][threadIdx.x];
            ts.x += a.x; ts.y += a.y; ts.z += a.z; ts.w += a.w;
            tq.x += b.x; tq.y += b.y; tq.z += b.z; tq.w += b.w;
        }
        f32x4* p = (f32x4*)partials + (size_t)blockIdx.x * 64;
        p[threadIdx.x] = ts;
        p[32 + threadIdx.x] = tq;
    }
}

__global__ __launch_bounds__(1024) void k_bn_fin2(const float* __restrict__ partials,
                                                  const float* __restrict__ gamma,
                                                  const float* __restrict__ beta,
                                                  float* __restrict__ scale,
                                                  float* __restrict__ shift) {
    const int d = threadIdx.x & 127;
    const int part = threadIdx.x >> 7;
    float s = 0.f, q = 0.f;
    for (int blk = part * 128; blk < part * 128 + 128; ++blk) {
        s += partials[(size_t)blk * 256 + d];
        q += partials[(size_t)blk * 256 + 128 + d];
    }
    __shared__ float lss[8][128];
    __shared__ float lqq[8][128];
    lss[part][d] = s;
    lqq[part][d] = q;
    __syncthreads();
    if (threadIdx.x < 128) {
        float ts = 0.f, tq = 0.f;
#pragma unroll
        for (int p = 0; p < 8; ++p) { ts += lss[p][d]; tq += lqq[p][d]; }
        float mu = ts * (1.f / BN_TOT);
        float var = tq * (1.f / BN_TOT) - mu * mu;
        float sc = gamma[d] * rsqrtf(var + BN_EPS);
        scale[d] = sc;
        shift[d] = beta[d] - mu * sc;
    }
}

// ---------------- MFMA fusion, double-buffered; t half read as bf16 ----------------
__global__ __launch_bounds__(512) void k_mfma_fusion(const float* __restrict__ agg,
                                                     const unsigned int* __restrict__ tb,
                                                     const __bf16* __restrict__ f1_h,
                                                     const __bf16* __restrict__ f1_l,
                                                     const float* __restrict__ f_b1,
                                                     const float* __restrict__ scale,
                                                     const float* __restrict__ shift,
                                                     const float* __restrict__ g,
                                                     const float* __restrict__ c0p,
                                                     float* __restrict__ out) {
    const int tid = threadIdx.x;
    const int w = tid >> 6;
    const int l = tid & 63;
    const float c0v = *c0p;
    bf16x8 Fh[8], Fl[8];
    const int ncol = w * 16 + (l & 15);
#pragma unroll
    for (int kk = 0; kk < 8; ++kk) {
        const int k = kk * 32 + (l >> 4) * 8;
        Fh[kk] = *(const bf16x8*)&f1_h[ncol * 256 + k];
        Fl[kk] = *(const bf16x8*)&f1_l[ncol * 256 + k];
    }
    const float b1c = f_b1[ncol];
    const float gc = g[ncol];
    __shared__ __align__(16) __bf16 ch_[2][32 * 256];
    __shared__ float part[8][32];
    const int srow = tid >> 4;
    const int scb = (tid & 15) * 16;
    const bool isagg = scb < 128;
    float4 sc4[4], sh4[4];
    if (isagg) {
#pragma unroll
        for (int q = 0; q < 4; ++q) {
            sc4[q] = *(const float4*)&scale[scb + q * 4];
            sh4[q] = *(const float4*)&shift[scb + q * 4];
        }
    }
    const int nchunks = BN_TOT / 32;
    float4 q[4];
    uint4 qu[2];
    auto loadc = [&](int chk) {
        if (isagg) {
            const float* srcp = agg + (size_t)(chk * 32 + srow) * D_ + scb;
#pragma unroll
            for (int qq = 0; qq < 4; ++qq) q[qq] = *(const float4*)(srcp + qq * 4);
        } else {
            const unsigned int* srcp = tb + (size_t)(chk * 32 + srow) * 64 + ((scb - 128) >> 1);
            qu[0] = *(const uint4*)srcp;
            qu[1] = *(const uint4*)(srcp + 4);
        }
    };
    auto storec = [&](int buf) {
        if (isagg) {
            float v[16];
#pragma unroll
            for (int qq = 0; qq < 4; ++qq) {
                float4 p = q[qq];
                p.x = fmaxf(p.x * sc4[qq].x + sh4[qq].x, 0.f);
                p.y = fmaxf(p.y * sc4[qq].y + sh4[qq].y, 0.f);
                p.z = fmaxf(p.z * sc4[qq].z + sh4[qq].z, 0.f);
                p.w = fmaxf(p.w * sc4[qq].w + sh4[qq].w, 0.f);
                v[qq * 4 + 0] = p.x; v[qq * 4 + 1] = p.y; v[qq * 4 + 2] = p.z; v[qq * 4 + 3] = p.w;
            }
#pragma unroll
            for (int hh = 0; hh < 2; ++hh) {
                const int c = scb + hh * 8;
                const int idx = srow * 256 + (c ^ ((srow & 7) * 8));
                *(bf16x8*)&ch_[buf][idx] = cvt8(v + hh * 8);
            }
        } else {
#pragma unroll
            for (int hh = 0; hh < 2; ++hh) {
                const int c = scb + hh * 8;
                const int idx = srow * 256 + (c ^ ((srow & 7) * 8));
                *(bf16x8*)&ch_[buf][idx] = *(const bf16x8*)&qu[hh];
            }
        }
    };
    loadc(blockIdx.x);
    storec(0);
    int cur = 0;
    for (int chk = blockIdx.x; chk < nchunks; chk += gridDim.x) {
        const int nxt = chk + gridDim.x;
        if (nxt < nchunks) loadc(nxt);
        __syncthreads();                 // (A) buf[cur] visible; part free
#pragma unroll
        for (int mt = 0; mt < 2; ++mt) {
            f32x4 acc = (f32x4){0.f, 0.f, 0.f, 0.f};
#pragma unroll
            for (int kk = 0; kk < 8; ++kk) {
                const int ai = (mt * 16 + (l & 15)) * 256 + ((kk * 32 + (l >> 4) * 8) ^ ((l & 7) * 8));
                bf16x8 ah = *(const bf16x8*)&ch_[cur][ai];
                acc = __builtin_amdgcn_mfma_f32_16x16x32_bf16(ah, Fh[kk], acc, 0, 0, 0);
                acc = __builtin_amdgcn_mfma_f32_16x16x32_bf16(ah, Fl[kk], acc, 0, 0, 0);
            }
            float p[4];
#pragma unroll
            for (int r = 0; r < 4; ++r) p[r] = fmaxf(acc[r] + b1c, 0.f) * gc;
#pragma unroll
            for (int r = 0; r < 4; ++r) {
                p[r] += __shfl_xor(p[r], 1);
                p[r] += __shfl_xor(p[r], 2);
                p[r] += __shfl_xor(p[r], 4);
                p[r] += __shfl_xor(p[r], 8);
            }
            if ((l & 15) == 0) {
#pragma unroll
                for (int r = 0; r < 4; ++r) part[w][mt * 16 + (l >> 4) * 4 + r] = p[r];
            }
        }
        __syncthreads();                 // (B) part ready; buf[cur] reads done
        if (tid < 32) {
            float s = c0v;
#pragma unroll
            for (int ww = 0; ww < 8; ++ww) s += part[ww][tid];
            out[chk * 32 + tid] = s;
        }
        if (nxt < nchunks) storec(cur ^ 1);
        cur ^= 1;
    }
}

// ---------------- launch ----------------
extern "C" void kernel_launch(void* const* d_in, const int* in_sizes, int n_in,
                              void* d_out, int out_size, void* d_ws, size_t ws_size,
                              hipStream_t stream) {
    const float* data     = (const float*)d_in[0];
    const int*   ei       = (const int*)d_in[1];
    const float* emb      = (const float*)d_in[2];
    const float* lin_w    = (const float*)d_in[3];
    const float* att_i    = (const float*)d_in[4];
    const float* att_j    = (const float*)d_in[5];
    const float* att_em_i = (const float*)d_in[6];
    const float* att_em_j = (const float*)d_in[7];
    const float* gnn_bias = (const float*)d_in[8];
    const float* bn_gamma = (const float*)d_in[9];
    const float* bn_beta  = (const float*)d_in[10];
    // q_w,q_b,k_w,k_b,temperature dead (W=1 -> softmax over single element -> attn==1)
    const float* v_w      = (const float*)d_in[15];
    const float* v_b      = (const float*)d_in[16];
    const float* f_w1     = (const float*)d_in[18];
    const float* f_b1     = (const float*)d_in[19];
    const float* f_w2     = (const float*)d_in[20];
    const float* f_b2     = (const float*)d_in[21];
    const float* out_w    = (const float*)d_in[22];
    const float* out_b    = (const float*)d_in[23];
    float* out = (float*)d_out;

    float* ws = (float*)d_ws;
    float* x      = ws;                                 // BN*D (free now; layout kept)
    float* tmat   = x + (size_t)BN_TOT * D_;            // BN*D region; tb uses first half
    float* agg    = tmat + (size_t)BN_TOT * D_;         // BN*D
    float* ni     = agg + (size_t)BN_TOT * D_;          // BN
    float* nj     = ni + BN_TOT;                        // BN
    float* eemi   = nj + BN_TOT;                        // N
    float* eemj   = eemi + N_;                          // N
    float* g      = eemj + N_;                          // D
    float* c0     = g + D_;                             // 1 (pad 8)
    float* scale  = c0 + 8;                             // D
    float* shift  = scale + D_;                         // D
    int* offs     = (int*)(shift + D_);                 // 1024 [zeroed]
    int* cursor   = offs + 1024;                        // 1024 [zeroed]
    float* bn_sum = (float*)(cursor + 1024);            // 128  [zeroed, unused]
    float* bn_sq  = bn_sum + D_;                        // 128  [zeroed, unused]
    int* csr_src  = (int*)(bn_sq + D_);                 // E
    float* exbuf  = (float*)(csr_src + E_);             // B*E (unused; layout kept)
    float* selfex = exbuf + (size_t)B_ * E_;            // BN (unused)
    float* denomv = selfex + BN_TOT;                    // BN (unused)
    __bf16* wcat_h = (__bf16*)(denomv + BN_TOT);        // 256*128
    __bf16* wcat_l = wcat_h + 256 * 128;                // 256*128
    __bf16* f1_h   = wcat_l + 256 * 128;                // 128*256
    __bf16* f1_l   = f1_h + 128 * 256;                  // 128*256
    float* partials = (float*)(f1_l + 128 * 256);       // 1024*256 floats = 1 MB
    unsigned int* xb = (unsigned int*)(partials + 1024 * 256);  // BN*64 uints
    unsigned int* tb = (unsigned int*)tmat;             // BN*64 uints (packed bf16 t)

    k_prep<<<508, 256, 0, stream>>>(lin_w, v_w, f_w1, emb, att_em_i, att_em_j,
                                    f_w2, f_b2, out_w, out_b,
                                    wcat_h, wcat_l, f1_h, f1_l,
                                    eemi, eemj, g, c0, offs);
    k_count<<<(E_ + 255) / 256, 256, 0, stream>>>(ei, offs);
    k_scan<<<1, 1024, 0, stream>>>(offs);
    k_scatter<<<(E_ + 255) / 256, 256, 0, stream>>>(ei, offs, cursor, csr_src);
    k_mfma_dual<<<500, 512, 0, stream>>>(data, wcat_h, wcat_l, v_b,
                                         att_i, att_j, eemi, eemj,
                                         ni, nj, xb, tb);
    k_sagg<<<BN_TOT / 4, 256, 0, stream>>>(xb, offs, csr_src, ni, nj, gnn_bias, agg);
    k_bn_part<<<1024, 256, 0, stream>>>(agg, partials);
    k_bn_fin2<<<1, 1024, 0, stream>>>(partials, bn_gamma, bn_beta, scale, shift);
    k_mfma_fusion<<<500, 512, 0, stream>>>(agg, tb, f1_h, f1_l, f_b1, scale, shift, g, c0, out);
}